// Round 1
// baseline (745.019 us; speedup 1.0000x reference)
//
#include <hip/hip_runtime.h>
#include <cstdint>
#include <cstddef>

// Problem constants (from reference): B=2048, IN=4, H=1024, L=4, OUT=256
#define Bsz   2048
#define INsz  4
#define Hsz   1024
#define Lsz   4
#define OUTsz 256

typedef float f32x4 __attribute__((ext_vector_type(4)));
typedef short s16x8 __attribute__((ext_vector_type(8)));

__device__ __forceinline__ unsigned short f2bf(float f) {
    union { float f; unsigned int u; } v; v.f = f;
    unsigned int r = 0x7FFFu + ((v.u >> 16) & 1u);
    return (unsigned short)((v.u + r) >> 16);
}

// Inline-asm MFMA: signature-proof vs builtin bf16/short ambiguity.
// D/C tied (%0). Chained MFMA->MFMA on same acc is HW-interlocked.
__device__ __forceinline__ void mfma_bf16(f32x4& c, s16x8 a, s16x8 b) {
    asm("v_mfma_f32_16x16x32_bf16 %0, %1, %2, %0" : "+v"(c) : "v"(a), "v"(b));
}

// ---------------- fp32 -> bf16 cast (8 elems/thread) ----------------
__global__ void cast_bf16_kernel(const float* __restrict__ in,
                                 unsigned short* __restrict__ out, int n8) {
    int i = blockIdx.x * blockDim.x + threadIdx.x;
    if (i >= n8) return;
    const float4* p = (const float4*)in;
    float4 a = p[2 * i], b = p[2 * i + 1];
    union { unsigned short s[8]; uint4 u; } o;
    o.s[0] = f2bf(a.x); o.s[1] = f2bf(a.y); o.s[2] = f2bf(a.z); o.s[3] = f2bf(a.w);
    o.s[4] = f2bf(b.x); o.s[5] = f2bf(b.y); o.s[6] = f2bf(b.z); o.s[7] = f2bf(b.w);
    ((uint4*)out)[i] = o.u;
}

// ---------------- x0 = input @ i2h_w.T + i2h_b  (K=4, tiny) ----------------
__global__ void i2h_kernel(const float* __restrict__ inp, const float* __restrict__ w,
                           const float* __restrict__ b, unsigned short* __restrict__ xb) {
    int idx = blockIdx.x * blockDim.x + threadIdx.x;  // over B*H
    int j = idx & (Hsz - 1);
    int m = idx >> 10;
    float4 xi = ((const float4*)inp)[m];
    float4 wj = ((const float4*)w)[j];
    float v = xi.x * wj.x + xi.y * wj.y + xi.z * wj.z + xi.w * wj.w + b[j];
    xb[idx] = f2bf(v);
}

// ---------------- bf16 GEMM: C[m][n] = sum_k A[m][k]*W[n][k] + bias[n] ----------------
// 128x128 tile, BK=64, 4 waves (2x2 of 64x64), 16x16x32 MFMA.
// blockIdx.z selects problem 0 (gi) or 1 (gh) -> one launch per layer.
// Reg-staged LDS with XOR chunk swizzle: LDS chunk s of row r holds global
// 16B-chunk (s ^ (r&7)) -> ds_read_b128 fragment reads are ~2-way conflict (free).
__global__ __launch_bounds__(256)
void gemm_dual(const unsigned short* __restrict__ A0, const unsigned short* __restrict__ B0,
               const float* __restrict__ bias0, float* __restrict__ C0,
               const unsigned short* __restrict__ A1, const unsigned short* __restrict__ B1,
               const float* __restrict__ bias1, float* __restrict__ C1,
               int M, int N, int K) {
    const unsigned short* A  = blockIdx.z ? A1 : A0;
    const unsigned short* Bw = blockIdx.z ? B1 : B0;
    const float* bias        = blockIdx.z ? bias1 : bias0;
    float* C                 = blockIdx.z ? C1 : C0;

    __shared__ __align__(16) unsigned short lA[128 * 64];
    __shared__ __align__(16) unsigned short lB[128 * 64];

    const int tid  = threadIdx.x;
    const int lane = tid & 63;
    const int wr   = (tid >> 6) >> 1;   // wave row (0..1)
    const int wc   = (tid >> 6) & 1;    // wave col (0..1)
    const long rowBase = (long)blockIdx.y * 128;
    const long colBase = (long)blockIdx.x * 128;

    f32x4 acc[4][4] = {};

    for (int k0 = 0; k0 < K; k0 += 64) {
        uint4 ta[4], tb[4];
        #pragma unroll
        for (int it = 0; it < 4; ++it) {
            int c = it * 256 + tid;       // chunk id 0..1023 (16B chunks)
            int r = c >> 3, j = c & 7;
            ta[it] = *(const uint4*)(A  + (rowBase + r) * (long)K + k0 + j * 8);
            tb[it] = *(const uint4*)(Bw + (colBase + r) * (long)K + k0 + j * 8);
        }
        __syncthreads();  // previous tile's reads complete before overwrite
        #pragma unroll
        for (int it = 0; it < 4; ++it) {
            int c = it * 256 + tid;
            int r = c >> 3, j = c & 7;
            int d = r * 64 + ((j ^ (r & 7)) << 3);
            *(uint4*)&lA[d] = ta[it];
            *(uint4*)&lB[d] = tb[it];
        }
        __syncthreads();
        #pragma unroll
        for (int kk = 0; kk < 2; ++kk) {
            s16x8 af[4], bf[4];
            #pragma unroll
            for (int mi = 0; mi < 4; ++mi) {
                int r = wr * 64 + mi * 16 + (lane & 15);
                int j = kk * 4 + (lane >> 4);
                af[mi] = *(const s16x8*)&lA[r * 64 + ((j ^ (r & 7)) << 3)];
            }
            #pragma unroll
            for (int ni = 0; ni < 4; ++ni) {
                int r = wc * 64 + ni * 16 + (lane & 15);
                int j = kk * 4 + (lane >> 4);
                bf[ni] = *(const s16x8*)&lB[r * 64 + ((j ^ (r & 7)) << 3)];
            }
            #pragma unroll
            for (int mi = 0; mi < 4; ++mi)
                #pragma unroll
                for (int ni = 0; ni < 4; ++ni)
                    mfma_bf16(acc[mi][ni], af[mi], bf[ni]);
        }
    }

    // Guard MFMA-write -> VALU-read hazard (inline-asm MFMA bypasses the
    // compiler's hazard recognizer).
    asm volatile("s_nop 7\n\ts_nop 7");

    #pragma unroll
    for (int mi = 0; mi < 4; ++mi) {
        #pragma unroll
        for (int ni = 0; ni < 4; ++ni) {
            long col = colBase + wc * 64 + ni * 16 + (lane & 15);
            float bv = bias[col];
            #pragma unroll
            for (int q = 0; q < 4; ++q) {
                long row = rowBase + wr * 64 + mi * 16 + (lane >> 4) * 4 + q;
                C[row * (long)N + col] = acc[mi][ni][q] + bv;
            }
        }
    }
}

// ---------------- GRU elementwise: h' = (1-z)*n + z*h ----------------
__global__ void gru_cell(const float* __restrict__ gi, const float* __restrict__ gh,
                         const float* __restrict__ hin, float* __restrict__ hout,
                         unsigned short* __restrict__ xb) {
    int idx = blockIdx.x * blockDim.x + threadIdx.x;  // over B*H/4
    int m  = idx >> 8;
    int jj = (idx & 255) << 2;
    long gb = (long)m * (3 * Hsz) + jj;
    long hb = (long)m * Hsz + jj;
    float4 ir  = *(const float4*)(gi + gb);
    float4 iz  = *(const float4*)(gi + gb + Hsz);
    float4 in4 = *(const float4*)(gi + gb + 2 * Hsz);
    float4 hr  = *(const float4*)(gh + gb);
    float4 hz  = *(const float4*)(gh + gb + Hsz);
    float4 hn  = *(const float4*)(gh + gb + 2 * Hsz);
    float4 hv  = *(const float4*)(hin + hb);
    float4 out;
#define GRU1(c)                                              \
    {                                                        \
        float rr = 1.f / (1.f + expf(-(ir.c + hr.c)));       \
        float zz = 1.f / (1.f + expf(-(iz.c + hz.c)));       \
        float nn = tanhf(in4.c + rr * hn.c);                 \
        out.c = (1.f - zz) * nn + zz * hv.c;                 \
    }
    GRU1(x) GRU1(y) GRU1(z) GRU1(w)
#undef GRU1
    *(float4*)(hout + hb) = out;
    ushort4 xo;
    xo.x = f2bf(out.x); xo.y = f2bf(out.y); xo.z = f2bf(out.z); xo.w = f2bf(out.w);
    *(ushort4*)(xb + hb) = xo;
}

extern "C" void kernel_launch(void* const* d_in, const int* in_sizes, int n_in,
                              void* d_out, int out_size, void* d_ws, size_t ws_size,
                              hipStream_t stream) {
    const float* input  = (const float*)d_in[0];
    const float* hidden = (const float*)d_in[1];
    const float* i2h_w  = (const float*)d_in[2];
    const float* i2h_b  = (const float*)d_in[3];
    const float* w_ih   = (const float*)d_in[4];
    const float* w_hh   = (const float*)d_in[5];
    const float* b_ih   = (const float*)d_in[6];
    const float* b_hh   = (const float*)d_in[7];
    const float* dec_w  = (const float*)d_in[8];
    const float* dec_b  = (const float*)d_in[9];

    float* logits = (float*)d_out;                       // [B, OUT]
    float* new_h  = (float*)d_out + (size_t)Bsz * OUTsz; // [L, B, H]

    // Workspace layout (needs ~117 MB; all sizes 256B-aligned already)
    char* p = (char*)d_ws;
    unsigned short* wih16  = (unsigned short*)p; p += (size_t)Lsz * 3 * Hsz * Hsz * 2;
    unsigned short* whh16  = (unsigned short*)p; p += (size_t)Lsz * 3 * Hsz * Hsz * 2;
    unsigned short* wdec16 = (unsigned short*)p; p += (size_t)OUTsz * Hsz * 2;
    unsigned short* h16    = (unsigned short*)p; p += (size_t)Lsz * Bsz * Hsz * 2;
    unsigned short* x16    = (unsigned short*)p; p += (size_t)Bsz * Hsz * 2;
    float* gi = (float*)p; p += (size_t)Bsz * 3 * Hsz * 4;
    float* gh = (float*)p; p += (size_t)Bsz * 3 * Hsz * 4;

    // 1) casts
    {
        int n8 = Lsz * 3 * Hsz * Hsz / 8;
        cast_bf16_kernel<<<(n8 + 255) / 256, 256, 0, stream>>>(w_ih, wih16, n8);
        cast_bf16_kernel<<<(n8 + 255) / 256, 256, 0, stream>>>(w_hh, whh16, n8);
    }
    {
        int n8 = OUTsz * Hsz / 8;
        cast_bf16_kernel<<<(n8 + 255) / 256, 256, 0, stream>>>(dec_w, wdec16, n8);
    }
    {
        int n8 = Lsz * Bsz * Hsz / 8;
        cast_bf16_kernel<<<(n8 + 255) / 256, 256, 0, stream>>>(hidden, h16, n8);
    }

    // 2) i2h projection -> x16 (bf16)
    i2h_kernel<<<(Bsz * Hsz) / 256, 256, 0, stream>>>(input, i2h_w, i2h_b, x16);

    // 3) GRU layers (sequential)
    for (int l = 0; l < Lsz; ++l) {
        dim3 grid(3 * Hsz / 128, Bsz / 128, 2);  // (24,16,2): z=0 -> gi, z=1 -> gh
        gemm_dual<<<grid, 256, 0, stream>>>(
            x16, wih16 + (size_t)l * 3 * Hsz * Hsz, b_ih + (size_t)l * 3 * Hsz, gi,
            h16 + (size_t)l * Bsz * Hsz, whh16 + (size_t)l * 3 * Hsz * Hsz,
            b_hh + (size_t)l * 3 * Hsz, gh,
            Bsz, 3 * Hsz, Hsz);
        gru_cell<<<(Bsz * Hsz / 4) / 256, 256, 0, stream>>>(
            gi, gh, hidden + (size_t)l * Bsz * Hsz, new_h + (size_t)l * Bsz * Hsz, x16);
    }

    // 4) decoder: logits = h3 @ dec_w.T + dec_b
    {
        dim3 grid(OUTsz / 128, Bsz / 128, 1);
        gemm_dual<<<grid, 256, 0, stream>>>(x16, wdec16, dec_b, logits,
                                            x16, wdec16, dec_b, logits,
                                            Bsz, OUTsz, Hsz);
    }
}

// Round 2
// 239.479 us; speedup vs baseline: 3.1110x; 3.1110x over previous
//
#include <hip/hip_runtime.h>
#include <cstdint>
#include <cstddef>

// Problem constants (from reference): B=2048, IN=4, H=1024, L=4, OUT=256
#define Bsz   2048
#define INsz  4
#define Hsz   1024
#define Lsz   4
#define OUTsz 256

typedef float f32x4 __attribute__((ext_vector_type(4)));
typedef short s16x8 __attribute__((ext_vector_type(8)));

typedef __attribute__((address_space(1))) void gvoid_t;  // global
typedef __attribute__((address_space(3))) void svoid_t;  // LDS

__device__ __forceinline__ unsigned short f2bf(float f) {
    union { float f; unsigned int u; } v; v.f = f;
    unsigned int r = 0x7FFFu + ((v.u >> 16) & 1u);
    return (unsigned short)((v.u + r) >> 16);
}

// Inline-asm MFMA: signature-proof vs builtin bf16/short ambiguity.
__device__ __forceinline__ void mfma_bf16(f32x4& c, s16x8 a, s16x8 b) {
    asm("v_mfma_f32_16x16x32_bf16 %0, %1, %2, %0" : "+v"(c) : "v"(a), "v"(b));
}

// ---------------- fp32 -> bf16 cast (8 elems/thread) ----------------
__global__ void cast_bf16_kernel(const float* __restrict__ in,
                                 unsigned short* __restrict__ out, int n8) {
    int i = blockIdx.x * blockDim.x + threadIdx.x;
    if (i >= n8) return;
    const float4* p = (const float4*)in;
    float4 a = p[2 * i], b = p[2 * i + 1];
    union { unsigned short s[8]; uint4 u; } o;
    o.s[0] = f2bf(a.x); o.s[1] = f2bf(a.y); o.s[2] = f2bf(a.z); o.s[3] = f2bf(a.w);
    o.s[4] = f2bf(b.x); o.s[5] = f2bf(b.y); o.s[6] = f2bf(b.z); o.s[7] = f2bf(b.w);
    ((uint4*)out)[i] = o.u;
}

// ---------------- x0 = input @ i2h_w.T + i2h_b  (K=4, tiny) ----------------
__global__ void i2h_kernel(const float* __restrict__ inp, const float* __restrict__ w,
                           const float* __restrict__ b, unsigned short* __restrict__ xb) {
    int idx = blockIdx.x * blockDim.x + threadIdx.x;  // over B*H
    int j = idx & (Hsz - 1);
    int m = idx >> 10;
    float4 xi = ((const float4*)inp)[m];
    float4 wj = ((const float4*)w)[j];
    float v = xi.x * wj.x + xi.y * wj.y + xi.z * wj.z + xi.w * wj.w + b[j];
    xb[idx] = f2bf(v);
}

// ---------------- bf16 GEMM: C[m][n] = sum_k A[m][k]*W[n][k] + bias[n] ----------------
// m97 structure: 128x128 tile, BK=64, 4 waves (2x2 of 64x64), 16x16x32 MFMA,
// global_load_lds width=16 direct-to-LDS staging, 2-barrier K-loop.
// LDS dest is linear (HW requirement); bank swizzle achieved by pre-swizzling
// the per-lane GLOBAL source (chunk j of row r holds global chunk j^(r&7)),
// reads use the same XOR -> conflict-free ds_read_b128 (verified 0 conflicts R1).
// 1D grid with bijective XCD swizzle (gridDim.x % 8 == 0 always here).
__global__ __launch_bounds__(256)
void gemm_dual(const unsigned short* __restrict__ A0, const unsigned short* __restrict__ B0,
               const float* __restrict__ bias0, float* __restrict__ C0,
               const unsigned short* __restrict__ A1, const unsigned short* __restrict__ B1,
               const float* __restrict__ bias1, float* __restrict__ C1,
               int M, int N, int K, int nx) {
    // XCD-aware bijective swizzle
    const int nwg = gridDim.x;
    const int cpx = nwg >> 3;
    const int bid = blockIdx.x;
    const int swz = (bid & 7) * cpx + (bid >> 3);
    const int per = nx * (M >> 7);
    const int z   = swz / per;
    const int idx = swz - z * per;
    const int my  = idx / nx;
    const int nxi = idx - my * nx;

    const unsigned short* A  = z ? A1 : A0;
    const unsigned short* Bw = z ? B1 : B0;
    const float* bias        = z ? bias1 : bias0;
    float* C                 = z ? C1 : C0;

    __shared__ __align__(16) unsigned short lA[128 * 64];
    __shared__ __align__(16) unsigned short lB[128 * 64];

    const int tid  = threadIdx.x;
    const int lane = tid & 63;
    const int w    = tid >> 6;
    const int wr   = w >> 1;   // wave row (0..1)
    const int wc   = w & 1;    // wave col (0..1)
    const long rowBase = (long)my * 128;
    const long colBase = (long)nxi * 128;

    // Per-lane source chunk geometry (constant across K-steps):
    // chunk c = cbase + lane; r = c>>3 (row in tile), j = c&7 (16B chunk in row),
    // source column chunk = j ^ (r&7)  (inverse-swizzle on the source side).
    f32x4 acc[4][4] = {};

    for (int k0 = 0; k0 < K; k0 += 64) {
        __syncthreads();  // previous tile's LDS reads complete before overwrite
        #pragma unroll
        for (int i = 0; i < 4; ++i) {
            const int cbase = (w * 4 + i) * 64;    // wave-uniform chunk base
            const int c = cbase + lane;
            const int r = c >> 3, j = c & 7;
            const int js = (j ^ (r & 7)) << 3;     // swizzled element offset in row
            const unsigned short* ga = A  + (rowBase + r) * (long)K + k0 + js;
            const unsigned short* gb = Bw + (colBase + r) * (long)K + k0 + js;
            __builtin_amdgcn_global_load_lds((gvoid_t*)ga, (svoid_t*)(lA + cbase * 8), 16, 0, 0);
            __builtin_amdgcn_global_load_lds((gvoid_t*)gb, (svoid_t*)(lB + cbase * 8), 16, 0, 0);
        }
        __syncthreads();  // compiler drains vmcnt(0) before barrier: tile ready

        #pragma unroll
        for (int kk = 0; kk < 2; ++kk) {
            s16x8 af[4], bf[4];
            #pragma unroll
            for (int mi = 0; mi < 4; ++mi) {
                int r = wr * 64 + mi * 16 + (lane & 15);
                int j = kk * 4 + (lane >> 4);
                af[mi] = *(const s16x8*)&lA[r * 64 + ((j ^ (r & 7)) << 3)];
            }
            #pragma unroll
            for (int ni = 0; ni < 4; ++ni) {
                int r = wc * 64 + ni * 16 + (lane & 15);
                int j = kk * 4 + (lane >> 4);
                bf[ni] = *(const s16x8*)&lB[r * 64 + ((j ^ (r & 7)) << 3)];
            }
            #pragma unroll
            for (int mi = 0; mi < 4; ++mi)
                #pragma unroll
                for (int ni = 0; ni < 4; ++ni)
                    mfma_bf16(acc[mi][ni], af[mi], bf[ni]);
        }
    }

    // Guard MFMA-write -> VALU-read hazard (inline-asm MFMA bypasses the
    // compiler's hazard recognizer).
    asm volatile("s_nop 7\n\ts_nop 7");

    #pragma unroll
    for (int mi = 0; mi < 4; ++mi) {
        #pragma unroll
        for (int ni = 0; ni < 4; ++ni) {
            long col = colBase + wc * 64 + ni * 16 + (lane & 15);
            float bv = bias[col];
            #pragma unroll
            for (int q = 0; q < 4; ++q) {
                long row = rowBase + wr * 64 + mi * 16 + (lane >> 4) * 4 + q;
                C[row * (long)N + col] = acc[mi][ni][q] + bv;
            }
        }
    }
}

// ---------------- GRU elementwise: h' = (1-z)*n + z*h ----------------
__global__ void gru_cell(const float* __restrict__ gi, const float* __restrict__ gh,
                         const float* __restrict__ hin, float* __restrict__ hout,
                         unsigned short* __restrict__ xb) {
    int idx = blockIdx.x * blockDim.x + threadIdx.x;  // over B*H/4
    int m  = idx >> 8;
    int jj = (idx & 255) << 2;
    long gb = (long)m * (3 * Hsz) + jj;
    long hb = (long)m * Hsz + jj;
    float4 ir  = *(const float4*)(gi + gb);
    float4 iz  = *(const float4*)(gi + gb + Hsz);
    float4 in4 = *(const float4*)(gi + gb + 2 * Hsz);
    float4 hr  = *(const float4*)(gh + gb);
    float4 hz  = *(const float4*)(gh + gb + Hsz);
    float4 hn  = *(const float4*)(gh + gb + 2 * Hsz);
    float4 hv  = *(const float4*)(hin + hb);
    float4 out;
#define GRU1(c)                                              \
    {                                                        \
        float rr = 1.f / (1.f + expf(-(ir.c + hr.c)));       \
        float zz = 1.f / (1.f + expf(-(iz.c + hz.c)));       \
        float nn = tanhf(in4.c + rr * hn.c);                 \
        out.c = (1.f - zz) * nn + zz * hv.c;                 \
    }
    GRU1(x) GRU1(y) GRU1(z) GRU1(w)
#undef GRU1
    *(float4*)(hout + hb) = out;
    ushort4 xo;
    xo.x = f2bf(out.x); xo.y = f2bf(out.y); xo.z = f2bf(out.z); xo.w = f2bf(out.w);
    *(ushort4*)(xb + hb) = xo;
}

extern "C" void kernel_launch(void* const* d_in, const int* in_sizes, int n_in,
                              void* d_out, int out_size, void* d_ws, size_t ws_size,
                              hipStream_t stream) {
    const float* input  = (const float*)d_in[0];
    const float* hidden = (const float*)d_in[1];
    const float* i2h_w  = (const float*)d_in[2];
    const float* i2h_b  = (const float*)d_in[3];
    const float* w_ih   = (const float*)d_in[4];
    const float* w_hh   = (const float*)d_in[5];
    const float* b_ih   = (const float*)d_in[6];
    const float* b_hh   = (const float*)d_in[7];
    const float* dec_w  = (const float*)d_in[8];
    const float* dec_b  = (const float*)d_in[9];

    float* logits = (float*)d_out;                       // [B, OUT]
    float* new_h  = (float*)d_out + (size_t)Bsz * OUTsz; // [L, B, H]

    // Workspace layout (~117 MB)
    char* p = (char*)d_ws;
    unsigned short* wih16  = (unsigned short*)p; p += (size_t)Lsz * 3 * Hsz * Hsz * 2;
    unsigned short* whh16  = (unsigned short*)p; p += (size_t)Lsz * 3 * Hsz * Hsz * 2;
    unsigned short* wdec16 = (unsigned short*)p; p += (size_t)OUTsz * Hsz * 2;
    unsigned short* h16    = (unsigned short*)p; p += (size_t)Lsz * Bsz * Hsz * 2;
    unsigned short* x16    = (unsigned short*)p; p += (size_t)Bsz * Hsz * 2;
    float* gi = (float*)p; p += (size_t)Bsz * 3 * Hsz * 4;
    float* gh = (float*)p; p += (size_t)Bsz * 3 * Hsz * 4;

    // 1) casts
    {
        int n8 = Lsz * 3 * Hsz * Hsz / 8;
        cast_bf16_kernel<<<(n8 + 255) / 256, 256, 0, stream>>>(w_ih, wih16, n8);
        cast_bf16_kernel<<<(n8 + 255) / 256, 256, 0, stream>>>(w_hh, whh16, n8);
    }
    {
        int n8 = OUTsz * Hsz / 8;
        cast_bf16_kernel<<<(n8 + 255) / 256, 256, 0, stream>>>(dec_w, wdec16, n8);
    }
    {
        int n8 = Lsz * Bsz * Hsz / 8;
        cast_bf16_kernel<<<(n8 + 255) / 256, 256, 0, stream>>>(hidden, h16, n8);
    }

    // 2) i2h projection -> x16 (bf16)
    i2h_kernel<<<(Bsz * Hsz) / 256, 256, 0, stream>>>(input, i2h_w, i2h_b, x16);

    // 3) GRU layers (sequential)
    for (int l = 0; l < Lsz; ++l) {
        int nx = 3 * Hsz / 128;                       // 24
        int blocks = 2 * nx * (Bsz / 128);            // 768 (both gi and gh)
        gemm_dual<<<blocks, 256, 0, stream>>>(
            x16, wih16 + (size_t)l * 3 * Hsz * Hsz, b_ih + (size_t)l * 3 * Hsz, gi,
            h16 + (size_t)l * Bsz * Hsz, whh16 + (size_t)l * 3 * Hsz * Hsz,
            b_hh + (size_t)l * 3 * Hsz, gh,
            Bsz, 3 * Hsz, Hsz, nx);
        gru_cell<<<(Bsz * Hsz / 4) / 256, 256, 0, stream>>>(
            gi, gh, hidden + (size_t)l * Bsz * Hsz, new_h + (size_t)l * Bsz * Hsz, x16);
    }

    // 4) decoder: logits = h3 @ dec_w.T + dec_b
    {
        int nx = OUTsz / 128;                          // 2
        int blocks = nx * (Bsz / 128);                 // 32 (single problem)
        gemm_dual<<<blocks, 256, 0, stream>>>(x16, wdec16, dec_b, logits,
                                              x16, wdec16, dec_b, logits,
                                              Bsz, OUTsz, Hsz, nx);
    }
}

// Round 3
// 195.164 us; speedup vs baseline: 3.8174x; 1.2271x over previous
//
#include <hip/hip_runtime.h>
#include <cstdint>
#include <cstddef>

// Problem constants (from reference): B=2048, IN=4, H=1024, L=4, OUT=256
#define Bsz   2048
#define INsz  4
#define Hsz   1024
#define Lsz   4
#define OUTsz 256

typedef float f32x4 __attribute__((ext_vector_type(4)));
typedef short s16x8 __attribute__((ext_vector_type(8)));

typedef __attribute__((address_space(1))) void gvoid_t;  // global
typedef __attribute__((address_space(3))) void svoid_t;  // LDS

__device__ __forceinline__ unsigned short f2bf(float f) {
    union { float f; unsigned int u; } v; v.f = f;
    unsigned int r = 0x7FFFu + ((v.u >> 16) & 1u);
    return (unsigned short)((v.u + r) >> 16);
}

__device__ __forceinline__ float sigm(float x) {
    return 1.0f / (1.0f + __expf(-x));
}
__device__ __forceinline__ float tanh_fast(float x) {
    float a = __expf(-2.0f * fabsf(x));
    float t = (1.0f - a) / (1.0f + a);
    return copysignf(t, x);
}

// Inline-asm MFMA: signature-proof vs builtin bf16/short ambiguity.
__device__ __forceinline__ void mfma_bf16(f32x4& c, s16x8 a, s16x8 b) {
    asm("v_mfma_f32_16x16x32_bf16 %0, %1, %2, %0" : "+v"(c) : "v"(a), "v"(b));
}

// ---------------- fp32 -> bf16 cast (8 elems/thread) ----------------
__global__ void cast_bf16_kernel(const float* __restrict__ in,
                                 unsigned short* __restrict__ out, int n8) {
    int i = blockIdx.x * blockDim.x + threadIdx.x;
    if (i >= n8) return;
    const float4* p = (const float4*)in;
    float4 a = p[2 * i], b = p[2 * i + 1];
    union { unsigned short s[8]; uint4 u; } o;
    o.s[0] = f2bf(a.x); o.s[1] = f2bf(a.y); o.s[2] = f2bf(a.z); o.s[3] = f2bf(a.w);
    o.s[4] = f2bf(b.x); o.s[5] = f2bf(b.y); o.s[6] = f2bf(b.z); o.s[7] = f2bf(b.w);
    ((uint4*)out)[i] = o.u;
}

// ---------------- cast + gate-group reorder for GRU weights ----------------
// in: [L*3H, H] fp32, rows = l*3H + gate*H + j.
// out row' = l*3H + (j>>4)*48 + gate*16 + (j&15)  -> a block of 16 j-columns
// has its r,z,n gate rows contiguous (16 each). total8 = L*3H*H/8.
__global__ void cast_reorder_w(const float* __restrict__ in,
                               unsigned short* __restrict__ out, int total8) {
    int i = blockIdx.x * blockDim.x + threadIdx.x;
    if (i >= total8) return;
    int k8  = i & (Hsz / 8 - 1);          // 128 chunks per row
    int row = i >> 7;
    int l    = row / (3 * Hsz);
    int lrow = row - l * (3 * Hsz);
    int gate = lrow >> 10;
    int j    = lrow & (Hsz - 1);
    int rowp = l * (3 * Hsz) + ((j >> 4) * 48) + gate * 16 + (j & 15);
    const float4* p = (const float4*)(in + (size_t)row * Hsz + k8 * 8);
    float4 a = p[0], b = p[1];
    union { unsigned short s[8]; uint4 u; } o;
    o.s[0] = f2bf(a.x); o.s[1] = f2bf(a.y); o.s[2] = f2bf(a.z); o.s[3] = f2bf(a.w);
    o.s[4] = f2bf(b.x); o.s[5] = f2bf(b.y); o.s[6] = f2bf(b.z); o.s[7] = f2bf(b.w);
    *(uint4*)(out + (size_t)rowp * Hsz + k8 * 8) = o.u;
}

// ---------------- x0 = input @ i2h_w.T + i2h_b  (K=4, tiny) ----------------
__global__ void i2h_kernel(const float* __restrict__ inp, const float* __restrict__ w,
                           const float* __restrict__ b, unsigned short* __restrict__ xb) {
    int idx = blockIdx.x * blockDim.x + threadIdx.x;  // over B*H
    int j = idx & (Hsz - 1);
    int m = idx >> 10;
    float4 xi = ((const float4*)inp)[m];
    float4 wj = ((const float4*)w)[j];
    float v = xi.x * wj.x + xi.y * wj.y + xi.z * wj.z + xi.w * wj.w + b[j];
    xb[idx] = f2bf(v);
}

// ---------------- Fused GRU layer: dual GEMM + gate math + blend ----------------
// Tile: 128 rows x 32 gate-columns (= 96 reordered W rows). 4 waves (2x2):
// wave = 64 rows x 16 gate-cols, ni = gate index (0=r,1=z,2=n) thanks to the
// 16-col gate-grouped weight reorder. Both gi (x@Wih^T) and gh (h@Whh^T)
// accumulate in-register; epilogue does the GRU cell and writes h' + bf16(h').
// Staging: global_load_lds width=16, linear LDS dest, source pre-swizzled
// (chunk j of row r holds global chunk j^(r&7)) -> conflict-free ds_read_b128.
__global__ __launch_bounds__(256, 2)
void gru_fused(const unsigned short* __restrict__ x,   // [B,H] bf16 layer input
               const unsigned short* __restrict__ hb,  // [B,H] bf16 h_{t-1}
               const unsigned short* __restrict__ Wi,  // [3H,H] bf16 reordered
               const unsigned short* __restrict__ Wh,  // [3H,H] bf16 reordered
               const float* __restrict__ bih,          // [3H] original layout
               const float* __restrict__ bhh,          // [3H] original layout
               const float* __restrict__ hold,         // [B,H] fp32 h_{t-1}
               float* __restrict__ hout,               // [B,H] fp32 h'
               unsigned short* __restrict__ xout) {    // [B,H] bf16 h'
    // XCD-aware bijective swizzle (grid = 512, %8 == 0)
    const int bid = blockIdx.x;
    const int swz = (bid & 7) * 64 + (bid >> 3);
    const int my  = swz >> 5;        // row tile 0..15
    const int nxi = swz & 31;        // col tile 0..31

    __shared__ __align__(16) unsigned short lX[128 * 64];
    __shared__ __align__(16) unsigned short lH[128 * 64];
    __shared__ __align__(16) unsigned short lBi[96 * 64];
    __shared__ __align__(16) unsigned short lBh[96 * 64];

    const int tid  = threadIdx.x;
    const int lane = tid & 63;
    const int w    = tid >> 6;
    const int wr   = w >> 1;         // wave row (0..1)
    const int wc   = w & 1;          // wave col / 16-col group (0..1)
    const long rowBase = (long)my * 128;
    const long colW    = (long)nxi * 96;   // reordered W row base

    f32x4 gia[4][3] = {};
    f32x4 gha[4][3] = {};

    for (int k0 = 0; k0 < Hsz; k0 += 64) {
        __syncthreads();  // previous tile's LDS reads complete before overwrite
        #pragma unroll
        for (int i = 0; i < 4; ++i) {            // lX, lH: 1024 chunks each
            const int cbase = (w * 4 + i) * 64;
            const int c = cbase + lane;
            const int r = c >> 3, jc = c & 7;
            const int js = (jc ^ (r & 7)) << 3;
            const long go = (rowBase + r) * (long)Hsz + k0 + js;
            __builtin_amdgcn_global_load_lds((gvoid_t*)(x  + go), (svoid_t*)(lX + cbase * 8), 16, 0, 0);
            __builtin_amdgcn_global_load_lds((gvoid_t*)(hb + go), (svoid_t*)(lH + cbase * 8), 16, 0, 0);
        }
        #pragma unroll
        for (int i = 0; i < 3; ++i) {            // lBi, lBh: 768 chunks each
            const int cbase = (w * 3 + i) * 64;
            const int c = cbase + lane;
            const int r = c >> 3, jc = c & 7;
            const int js = (jc ^ (r & 7)) << 3;
            const long go = (colW + r) * (long)Hsz + k0 + js;
            __builtin_amdgcn_global_load_lds((gvoid_t*)(Wi + go), (svoid_t*)(lBi + cbase * 8), 16, 0, 0);
            __builtin_amdgcn_global_load_lds((gvoid_t*)(Wh + go), (svoid_t*)(lBh + cbase * 8), 16, 0, 0);
        }
        __syncthreads();  // vmcnt(0) drained before barrier: tile ready

        #pragma unroll
        for (int kk = 0; kk < 2; ++kk) {
            s16x8 ax[4], ah[4], bi[3], bh[3];
            const int jk = kk * 4 + (lane >> 4);
            #pragma unroll
            for (int mi = 0; mi < 4; ++mi) {
                int r = wr * 64 + mi * 16 + (lane & 15);
                int off = r * 64 + ((jk ^ (r & 7)) << 3);
                ax[mi] = *(const s16x8*)&lX[off];
                ah[mi] = *(const s16x8*)&lH[off];
            }
            #pragma unroll
            for (int ni = 0; ni < 3; ++ni) {
                int r = wc * 48 + ni * 16 + (lane & 15);
                int off = r * 64 + ((jk ^ (r & 7)) << 3);
                bi[ni] = *(const s16x8*)&lBi[off];
                bh[ni] = *(const s16x8*)&lBh[off];
            }
            #pragma unroll
            for (int mi = 0; mi < 4; ++mi)
                #pragma unroll
                for (int ni = 0; ni < 3; ++ni) {
                    mfma_bf16(gia[mi][ni], ax[mi], bi[ni]);
                    mfma_bf16(gha[mi][ni], ah[mi], bh[ni]);
                }
        }
    }

    // Guard MFMA-write -> VALU-read hazard (inline-asm MFMA bypasses the
    // compiler's hazard recognizer).
    asm volatile("s_nop 7\n\ts_nop 7");

    // ---- GRU epilogue (all per-lane, no cross-lane) ----
    const int j = nxi * 32 + wc * 16 + (lane & 15);   // gate column 0..1023
    const float bir = bih[j],            bhr = bhh[j];
    const float biz = bih[Hsz + j],      bhz = bhh[Hsz + j];
    const float bin = bih[2 * Hsz + j],  bhn = bhh[2 * Hsz + j];

    #pragma unroll
    for (int mi = 0; mi < 4; ++mi) {
        #pragma unroll
        for (int q = 0; q < 4; ++q) {
            long row = rowBase + wr * 64 + mi * 16 + ((lane >> 4) << 2) + q;
            float r = sigm(gia[mi][0][q] + bir + gha[mi][0][q] + bhr);
            float z = sigm(gia[mi][1][q] + biz + gha[mi][1][q] + bhz);
            float n = tanh_fast(gia[mi][2][q] + bin + r * (gha[mi][2][q] + bhn));
            float hv = hold[row * Hsz + j];
            float o  = (1.0f - z) * n + z * hv;
            hout[row * Hsz + j] = o;
            xout[row * Hsz + j] = f2bf(o);
        }
    }
}

// ---------------- decoder GEMM: C = A @ W^T + b (128x128 tile, m97 structure) ----------------
__global__ __launch_bounds__(256)
void gemm_dec(const unsigned short* __restrict__ A, const unsigned short* __restrict__ Bw,
              const float* __restrict__ bias, float* __restrict__ C,
              int M, int N, int K, int nx) {
    const int nwg = gridDim.x;
    const int cpx = nwg >> 3;
    const int bid = blockIdx.x;
    const int swz = (bid & 7) * cpx + (bid >> 3);
    const int my  = swz / nx;
    const int nxi = swz - my * nx;

    __shared__ __align__(16) unsigned short lA[128 * 64];
    __shared__ __align__(16) unsigned short lB[128 * 64];

    const int tid  = threadIdx.x;
    const int lane = tid & 63;
    const int w    = tid >> 6;
    const int wr   = w >> 1;
    const int wc   = w & 1;
    const long rowBase = (long)my * 128;
    const long colBase = (long)nxi * 128;

    f32x4 acc[4][4] = {};

    for (int k0 = 0; k0 < K; k0 += 64) {
        __syncthreads();
        #pragma unroll
        for (int i = 0; i < 4; ++i) {
            const int cbase = (w * 4 + i) * 64;
            const int c = cbase + lane;
            const int r = c >> 3, jc = c & 7;
            const int js = (jc ^ (r & 7)) << 3;
            __builtin_amdgcn_global_load_lds((gvoid_t*)(A  + (rowBase + r) * (long)K + k0 + js),
                                             (svoid_t*)(lA + cbase * 8), 16, 0, 0);
            __builtin_amdgcn_global_load_lds((gvoid_t*)(Bw + (colBase + r) * (long)K + k0 + js),
                                             (svoid_t*)(lB + cbase * 8), 16, 0, 0);
        }
        __syncthreads();

        #pragma unroll
        for (int kk = 0; kk < 2; ++kk) {
            s16x8 af[4], bf[4];
            const int jk = kk * 4 + (lane >> 4);
            #pragma unroll
            for (int mi = 0; mi < 4; ++mi) {
                int r = wr * 64 + mi * 16 + (lane & 15);
                af[mi] = *(const s16x8*)&lA[r * 64 + ((jk ^ (r & 7)) << 3)];
            }
            #pragma unroll
            for (int ni = 0; ni < 4; ++ni) {
                int r = wc * 64 + ni * 16 + (lane & 15);
                bf[ni] = *(const s16x8*)&lB[r * 64 + ((jk ^ (r & 7)) << 3)];
            }
            #pragma unroll
            for (int mi = 0; mi < 4; ++mi)
                #pragma unroll
                for (int ni = 0; ni < 4; ++ni)
                    mfma_bf16(acc[mi][ni], af[mi], bf[ni]);
        }
    }

    asm volatile("s_nop 7\n\ts_nop 7");

    #pragma unroll
    for (int mi = 0; mi < 4; ++mi) {
        #pragma unroll
        for (int ni = 0; ni < 4; ++ni) {
            long col = colBase + wc * 64 + ni * 16 + (lane & 15);
            float bv = bias[col];
            #pragma unroll
            for (int q = 0; q < 4; ++q) {
                long row = rowBase + wr * 64 + mi * 16 + (lane >> 4) * 4 + q;
                C[row * (long)N + col] = acc[mi][ni][q] + bv;
            }
        }
    }
}

extern "C" void kernel_launch(void* const* d_in, const int* in_sizes, int n_in,
                              void* d_out, int out_size, void* d_ws, size_t ws_size,
                              hipStream_t stream) {
    const float* input  = (const float*)d_in[0];
    const float* hidden = (const float*)d_in[1];
    const float* i2h_w  = (const float*)d_in[2];
    const float* i2h_b  = (const float*)d_in[3];
    const float* w_ih   = (const float*)d_in[4];
    const float* w_hh   = (const float*)d_in[5];
    const float* b_ih   = (const float*)d_in[6];
    const float* b_hh   = (const float*)d_in[7];
    const float* dec_w  = (const float*)d_in[8];
    const float* dec_b  = (const float*)d_in[9];

    float* logits = (float*)d_out;                       // [B, OUT]
    float* new_h  = (float*)d_out + (size_t)Bsz * OUTsz; // [L, B, H]

    // Workspace layout (~76 MB)
    char* p = (char*)d_ws;
    unsigned short* wih16  = (unsigned short*)p; p += (size_t)Lsz * 3 * Hsz * Hsz * 2;
    unsigned short* whh16  = (unsigned short*)p; p += (size_t)Lsz * 3 * Hsz * Hsz * 2;
    unsigned short* wdec16 = (unsigned short*)p; p += (size_t)OUTsz * Hsz * 2;
    unsigned short* h16    = (unsigned short*)p; p += (size_t)Lsz * Bsz * Hsz * 2;
    unsigned short* xb0    = (unsigned short*)p; p += (size_t)Bsz * Hsz * 2;
    unsigned short* xb1    = (unsigned short*)p; p += (size_t)Bsz * Hsz * 2;
    unsigned short* xbuf[2] = { xb0, xb1 };

    // 1) casts (+ gate-group reorder for GRU weights)
    {
        int n8 = Lsz * 3 * Hsz * Hsz / 8;
        cast_reorder_w<<<(n8 + 255) / 256, 256, 0, stream>>>(w_ih, wih16, n8);
        cast_reorder_w<<<(n8 + 255) / 256, 256, 0, stream>>>(w_hh, whh16, n8);
    }
    {
        int n8 = OUTsz * Hsz / 8;
        cast_bf16_kernel<<<(n8 + 255) / 256, 256, 0, stream>>>(dec_w, wdec16, n8);
    }
    {
        int n8 = Lsz * Bsz * Hsz / 8;
        cast_bf16_kernel<<<(n8 + 255) / 256, 256, 0, stream>>>(hidden, h16, n8);
    }

    // 2) i2h projection -> xb0 (bf16)
    i2h_kernel<<<(Bsz * Hsz) / 256, 256, 0, stream>>>(input, i2h_w, i2h_b, xb0);

    // 3) fused GRU layers (one launch each)
    for (int l = 0; l < Lsz; ++l) {
        gru_fused<<<512, 256, 0, stream>>>(
            xbuf[l & 1],
            h16 + (size_t)l * Bsz * Hsz,
            wih16 + (size_t)l * 3 * Hsz * Hsz,
            whh16 + (size_t)l * 3 * Hsz * Hsz,
            b_ih + (size_t)l * 3 * Hsz,
            b_hh + (size_t)l * 3 * Hsz,
            hidden + (size_t)l * Bsz * Hsz,
            new_h + (size_t)l * Bsz * Hsz,
            xbuf[(l + 1) & 1]);
    }

    // 4) decoder: logits = h3 @ dec_w.T + dec_b   (h3 is in xbuf[0] after 4 layers)
    {
        int nx = OUTsz / 128;                          // 2
        int blocks = nx * (Bsz / 128);                 // 32
        gemm_dec<<<blocks, 256, 0, stream>>>(xbuf[Lsz & 1], wdec16, dec_b, logits,
                                             Bsz, OUTsz, Hsz, nx);
    }
}

// Round 4
// 182.009 us; speedup vs baseline: 4.0933x; 1.0723x over previous
//
#include <hip/hip_runtime.h>
#include <cstdint>
#include <cstddef>

// Problem constants (from reference): B=2048, IN=4, H=1024, L=4, OUT=256
#define Bsz   2048
#define INsz  4
#define Hsz   1024
#define Lsz   4
#define OUTsz 256

typedef float f32x4 __attribute__((ext_vector_type(4)));
typedef short s16x8 __attribute__((ext_vector_type(8)));

typedef __attribute__((address_space(1))) void gvoid_t;  // global
typedef __attribute__((address_space(3))) void svoid_t;  // LDS

__device__ __forceinline__ unsigned short f2bf(float f) {
    union { float f; unsigned int u; } v; v.f = f;
    unsigned int r = 0x7FFFu + ((v.u >> 16) & 1u);
    return (unsigned short)((v.u + r) >> 16);
}

__device__ __forceinline__ float sigm(float x) {
    return 1.0f / (1.0f + __expf(-x));
}
__device__ __forceinline__ float tanh_fast(float x) {
    float a = __expf(-2.0f * fabsf(x));
    float t = (1.0f - a) / (1.0f + a);
    return copysignf(t, x);
}

// Inline-asm MFMA: signature-proof vs builtin bf16/short ambiguity.
__device__ __forceinline__ void mfma_bf16(f32x4& c, s16x8 a, s16x8 b) {
    asm("v_mfma_f32_16x16x32_bf16 %0, %1, %2, %0" : "+v"(c) : "v"(a), "v"(b));
}

// ---------------- fp32 -> bf16 cast (8 elems/thread) ----------------
__global__ void cast_bf16_kernel(const float* __restrict__ in,
                                 unsigned short* __restrict__ out, int n8) {
    int i = blockIdx.x * blockDim.x + threadIdx.x;
    if (i >= n8) return;
    const float4* p = (const float4*)in;
    float4 a = p[2 * i], b = p[2 * i + 1];
    union { unsigned short s[8]; uint4 u; } o;
    o.s[0] = f2bf(a.x); o.s[1] = f2bf(a.y); o.s[2] = f2bf(a.z); o.s[3] = f2bf(a.w);
    o.s[4] = f2bf(b.x); o.s[5] = f2bf(b.y); o.s[6] = f2bf(b.z); o.s[7] = f2bf(b.w);
    ((uint4*)out)[i] = o.u;
}

// ---------------- cast + gate-group reorder for GRU weights ----------------
// in: [L*3H, H] fp32, rows = l*3H + gate*H + j.
// out row' = l*3H + (j>>4)*48 + gate*16 + (j&15)  -> a block of 16 j-columns
// has its r,z,n gate rows contiguous (16 each). total8 = L*3H*H/8.
__global__ void cast_reorder_w(const float* __restrict__ in,
                               unsigned short* __restrict__ out, int total8) {
    int i = blockIdx.x * blockDim.x + threadIdx.x;
    if (i >= total8) return;
    int k8  = i & (Hsz / 8 - 1);          // 128 chunks per row
    int row = i >> 7;
    int l    = row / (3 * Hsz);
    int lrow = row - l * (3 * Hsz);
    int gate = lrow >> 10;
    int j    = lrow & (Hsz - 1);
    int rowp = l * (3 * Hsz) + ((j >> 4) * 48) + gate * 16 + (j & 15);
    const float4* p = (const float4*)(in + (size_t)row * Hsz + k8 * 8);
    float4 a = p[0], b = p[1];
    union { unsigned short s[8]; uint4 u; } o;
    o.s[0] = f2bf(a.x); o.s[1] = f2bf(a.y); o.s[2] = f2bf(a.z); o.s[3] = f2bf(a.w);
    o.s[4] = f2bf(b.x); o.s[5] = f2bf(b.y); o.s[6] = f2bf(b.z); o.s[7] = f2bf(b.w);
    *(uint4*)(out + (size_t)rowp * Hsz + k8 * 8) = o.u;
}

// ---------------- x0 = input @ i2h_w.T + i2h_b  (K=4, tiny) ----------------
__global__ void i2h_kernel(const float* __restrict__ inp, const float* __restrict__ w,
                           const float* __restrict__ b, unsigned short* __restrict__ xb) {
    int idx = blockIdx.x * blockDim.x + threadIdx.x;  // over B*H
    int j = idx & (Hsz - 1);
    int m = idx >> 10;
    float4 xi = ((const float4*)inp)[m];
    float4 wj = ((const float4*)w)[j];
    float v = xi.x * wj.x + xi.y * wj.y + xi.z * wj.z + xi.w * wj.w + b[j];
    xb[idx] = f2bf(v);
}

// ---------------- Fused GRU layer: concat-K dual GEMM + gate math ----------------
// Concat-K view: gates(r,z) = [x;h] @ [Wi_rz; Wh_rz]^T accumulated over K=2048
// (phase 0: A=x,B=Wi for k<1024; phase 1: A=h,B=Wh). n-gate keeps separate
// accumulators i_n (phase 0) and h_n (phase 1). Tile: 128 rows x 32 gate-cols
// (96 reordered W rows), 4 waves (2x2), wave = 64 rows x 16 cols, ni = gate.
// 1-deep pipelined 2-phase loop: STAGE(t+1, buf^1) issued before COMPUTE(t),
// one vmcnt(0)+barrier per tile (T3-min). LDS double buffer 2x28KB -> 2 blk/CU.
// Staging: global_load_lds w=16, linear LDS dest, source pre-swizzled
// (chunk j of row r holds global chunk j^(r&7)) -> conflict-free ds_read_b128.
#define BUFSZ (224 * 64)   // (128 A-rows + 96 B-rows) * 64 k, elements
__global__ __launch_bounds__(256, 2)
void gru_fused(const unsigned short* __restrict__ x,   // [B,H] bf16 layer input
               const unsigned short* __restrict__ hb,  // [B,H] bf16 h_{t-1}
               const unsigned short* __restrict__ Wi,  // [3H,H] bf16 reordered
               const unsigned short* __restrict__ Wh,  // [3H,H] bf16 reordered
               const float* __restrict__ bih,          // [3H] original layout
               const float* __restrict__ bhh,          // [3H] original layout
               const float* __restrict__ hold,         // [B,H] fp32 h_{t-1}
               float* __restrict__ hout,               // [B,H] fp32 h'
               unsigned short* __restrict__ xout) {    // [B,H] bf16 h'
    // XCD-aware bijective swizzle (grid = 512, %8 == 0)
    const int bid = blockIdx.x;
    const int swz = (bid & 7) * 64 + (bid >> 3);
    const int my  = swz >> 5;        // row tile 0..15
    const int nxi = swz & 31;        // col tile 0..31

    __shared__ __align__(16) unsigned short lds[2 * BUFSZ];

    const int tid  = threadIdx.x;
    const int lane = tid & 63;
    const int w    = tid >> 6;
    const int wr   = w >> 1;         // wave row (0..1)
    const int wc   = w & 1;          // wave col / 16-col group (0..1)
    const long rowBase = (long)my * 128;
    const long colW    = (long)nxi * 96;   // reordered W row base

    f32x4 rz[4][2] = {};   // r,z gate sums (i+h), accumulated over all 32 steps
    f32x4 nin[4] = {};     // i_n (phase 0)
    f32x4 nhn[4] = {};     // h_n (phase 1)

    // Issue the 7 global_load_lds for K-tile tn into buffer buf.
    auto STAGE = [&](int tn, int buf) {
        const unsigned short* Ap = (tn < 16) ? x : hb;
        const unsigned short* Wp = (tn < 16) ? Wi : Wh;
        const long koff = (long)(tn & 15) * 64;
        unsigned short* la = lds + buf * BUFSZ;
        unsigned short* lb = la + 128 * 64;
        #pragma unroll
        for (int i = 0; i < 4; ++i) {            // A-tile: 1024 chunks
            const int cbase = (w * 4 + i) * 64;
            const int c = cbase + lane;
            const int r = c >> 3, jc = c & 7;
            const int js = (jc ^ (r & 7)) << 3;
            __builtin_amdgcn_global_load_lds(
                (gvoid_t*)(Ap + (rowBase + r) * (long)Hsz + koff + js),
                (svoid_t*)(la + cbase * 8), 16, 0, 0);
        }
        #pragma unroll
        for (int i = 0; i < 3; ++i) {            // B-tile: 768 chunks
            const int cbase = (w * 3 + i) * 64;
            const int c = cbase + lane;
            const int r = c >> 3, jc = c & 7;
            const int js = (jc ^ (r & 7)) << 3;
            __builtin_amdgcn_global_load_lds(
                (gvoid_t*)(Wp + (colW + r) * (long)Hsz + koff + js),
                (svoid_t*)(lb + cbase * 8), 16, 0, 0);
        }
    };

    auto COMPUTE = [&](int t) {
        const unsigned short* la = lds + (t & 1) * BUFSZ;
        const unsigned short* lb = la + 128 * 64;
        const bool ph0 = (t < 16);               // wave-uniform
        #pragma unroll
        for (int kk = 0; kk < 2; ++kk) {
            s16x8 av[4], bv[3];
            const int jk = kk * 4 + (lane >> 4);
            #pragma unroll
            for (int mi = 0; mi < 4; ++mi) {
                int r = wr * 64 + mi * 16 + (lane & 15);
                av[mi] = *(const s16x8*)&la[r * 64 + ((jk ^ (r & 7)) << 3)];
            }
            #pragma unroll
            for (int ni = 0; ni < 3; ++ni) {
                int r = wc * 48 + ni * 16 + (lane & 15);
                bv[ni] = *(const s16x8*)&lb[r * 64 + ((jk ^ (r & 7)) << 3)];
            }
            __builtin_amdgcn_s_setprio(1);
            #pragma unroll
            for (int mi = 0; mi < 4; ++mi) {
                mfma_bf16(rz[mi][0], av[mi], bv[0]);
                mfma_bf16(rz[mi][1], av[mi], bv[1]);
            }
            if (ph0) {
                #pragma unroll
                for (int mi = 0; mi < 4; ++mi) mfma_bf16(nin[mi], av[mi], bv[2]);
            } else {
                #pragma unroll
                for (int mi = 0; mi < 4; ++mi) mfma_bf16(nhn[mi], av[mi], bv[2]);
            }
            __builtin_amdgcn_s_setprio(0);
        }
    };

    STAGE(0, 0);
    __syncthreads();                  // vmcnt(0) drain + barrier: tile 0 ready
    #pragma unroll 2
    for (int t = 0; t < 31; ++t) {
        STAGE(t + 1, (t + 1) & 1);    // overlaps with COMPUTE(t)
        COMPUTE(t);
        __syncthreads();              // drains t+1 loads; protects buf reuse
    }
    COMPUTE(31);

    // Guard MFMA-write -> VALU-read hazard (inline-asm MFMA bypasses the
    // compiler's hazard recognizer).
    asm volatile("s_nop 7\n\ts_nop 7");

    // ---- GRU epilogue (all per-lane, no cross-lane) ----
    const int j = nxi * 32 + wc * 16 + (lane & 15);   // gate column 0..1023
    const float br = bih[j]           + bhh[j];
    const float bz = bih[Hsz + j]     + bhh[Hsz + j];
    const float bin = bih[2 * Hsz + j];
    const float bhn = bhh[2 * Hsz + j];

    #pragma unroll
    for (int mi = 0; mi < 4; ++mi) {
        #pragma unroll
        for (int q = 0; q < 4; ++q) {
            long row = rowBase + wr * 64 + mi * 16 + ((lane >> 4) << 2) + q;
            float r = sigm(rz[mi][0][q] + br);
            float z = sigm(rz[mi][1][q] + bz);
            float n = tanh_fast(nin[mi][q] + bin + r * (nhn[mi][q] + bhn));
            float hv = hold[row * Hsz + j];
            float o  = (1.0f - z) * n + z * hv;
            hout[row * Hsz + j] = o;
            xout[row * Hsz + j] = f2bf(o);
        }
    }
}

// ---------------- decoder GEMM: C = A @ W^T + b (128x128 tile, m97 structure) ----------------
__global__ __launch_bounds__(256)
void gemm_dec(const unsigned short* __restrict__ A, const unsigned short* __restrict__ Bw,
              const float* __restrict__ bias, float* __restrict__ C,
              int M, int N, int K, int nx) {
    const int nwg = gridDim.x;
    const int cpx = nwg >> 3;
    const int bid = blockIdx.x;
    const int swz = (bid & 7) * cpx + (bid >> 3);
    const int my  = swz / nx;
    const int nxi = swz - my * nx;

    __shared__ __align__(16) unsigned short lA[128 * 64];
    __shared__ __align__(16) unsigned short lB[128 * 64];

    const int tid  = threadIdx.x;
    const int lane = tid & 63;
    const int w    = tid >> 6;
    const int wr   = w >> 1;
    const int wc   = w & 1;
    const long rowBase = (long)my * 128;
    const long colBase = (long)nxi * 128;

    f32x4 acc[4][4] = {};

    for (int k0 = 0; k0 < K; k0 += 64) {
        __syncthreads();
        #pragma unroll
        for (int i = 0; i < 4; ++i) {
            const int cbase = (w * 4 + i) * 64;
            const int c = cbase + lane;
            const int r = c >> 3, jc = c & 7;
            const int js = (jc ^ (r & 7)) << 3;
            __builtin_amdgcn_global_load_lds((gvoid_t*)(A  + (rowBase + r) * (long)K + k0 + js),
                                             (svoid_t*)(lA + cbase * 8), 16, 0, 0);
            __builtin_amdgcn_global_load_lds((gvoid_t*)(Bw + (colBase + r) * (long)K + k0 + js),
                                             (svoid_t*)(lB + cbase * 8), 16, 0, 0);
        }
        __syncthreads();

        #pragma unroll
        for (int kk = 0; kk < 2; ++kk) {
            s16x8 af[4], bf[4];
            const int jk = kk * 4 + (lane >> 4);
            #pragma unroll
            for (int mi = 0; mi < 4; ++mi) {
                int r = wr * 64 + mi * 16 + (lane & 15);
                af[mi] = *(const s16x8*)&lA[r * 64 + ((jk ^ (r & 7)) << 3)];
            }
            #pragma unroll
            for (int ni = 0; ni < 4; ++ni) {
                int r = wc * 64 + ni * 16 + (lane & 15);
                bf[ni] = *(const s16x8*)&lB[r * 64 + ((jk ^ (r & 7)) << 3)];
            }
            #pragma unroll
            for (int mi = 0; mi < 4; ++mi)
                #pragma unroll
                for (int ni = 0; ni < 4; ++ni)
                    mfma_bf16(acc[mi][ni], af[mi], bf[ni]);
        }
    }

    asm volatile("s_nop 7\n\ts_nop 7");

    #pragma unroll
    for (int mi = 0; mi < 4; ++mi) {
        #pragma unroll
        for (int ni = 0; ni < 4; ++ni) {
            long col = colBase + wc * 64 + ni * 16 + (lane & 15);
            float bv = bias[col];
            #pragma unroll
            for (int q = 0; q < 4; ++q) {
                long row = rowBase + wr * 64 + mi * 16 + (lane >> 4) * 4 + q;
                C[row * (long)N + col] = acc[mi][ni][q] + bv;
            }
        }
    }
}

extern "C" void kernel_launch(void* const* d_in, const int* in_sizes, int n_in,
                              void* d_out, int out_size, void* d_ws, size_t ws_size,
                              hipStream_t stream) {
    const float* input  = (const float*)d_in[0];
    const float* hidden = (const float*)d_in[1];
    const float* i2h_w  = (const float*)d_in[2];
    const float* i2h_b  = (const float*)d_in[3];
    const float* w_ih   = (const float*)d_in[4];
    const float* w_hh   = (const float*)d_in[5];
    const float* b_ih   = (const float*)d_in[6];
    const float* b_hh   = (const float*)d_in[7];
    const float* dec_w  = (const float*)d_in[8];
    const float* dec_b  = (const float*)d_in[9];

    float* logits = (float*)d_out;                       // [B, OUT]
    float* new_h  = (float*)d_out + (size_t)Bsz * OUTsz; // [L, B, H]

    // Workspace layout (~76 MB)
    char* p = (char*)d_ws;
    unsigned short* wih16  = (unsigned short*)p; p += (size_t)Lsz * 3 * Hsz * Hsz * 2;
    unsigned short* whh16  = (unsigned short*)p; p += (size_t)Lsz * 3 * Hsz * Hsz * 2;
    unsigned short* wdec16 = (unsigned short*)p; p += (size_t)OUTsz * Hsz * 2;
    unsigned short* h16    = (unsigned short*)p; p += (size_t)Lsz * Bsz * Hsz * 2;
    unsigned short* xb0    = (unsigned short*)p; p += (size_t)Bsz * Hsz * 2;
    unsigned short* xb1    = (unsigned short*)p; p += (size_t)Bsz * Hsz * 2;
    unsigned short* xbuf[2] = { xb0, xb1 };

    // 1) casts (+ gate-group reorder for GRU weights)
    {
        int n8 = Lsz * 3 * Hsz * Hsz / 8;
        cast_reorder_w<<<(n8 + 255) / 256, 256, 0, stream>>>(w_ih, wih16, n8);
        cast_reorder_w<<<(n8 + 255) / 256, 256, 0, stream>>>(w_hh, whh16, n8);
    }
    {
        int n8 = OUTsz * Hsz / 8;
        cast_bf16_kernel<<<(n8 + 255) / 256, 256, 0, stream>>>(dec_w, wdec16, n8);
    }
    {
        int n8 = Lsz * Bsz * Hsz / 8;
        cast_bf16_kernel<<<(n8 + 255) / 256, 256, 0, stream>>>(hidden, h16, n8);
    }

    // 2) i2h projection -> xb0 (bf16)
    i2h_kernel<<<(Bsz * Hsz) / 256, 256, 0, stream>>>(input, i2h_b ? input : input, i2h_b, xb0);
    // (call fixed below — keep signature explicit)
    i2h_kernel<<<(Bsz * Hsz) / 256, 256, 0, stream>>>(input, i2h_w, i2h_b, xb0);

    // 3) fused GRU layers (one launch each)
    for (int l = 0; l < Lsz; ++l) {
        gru_fused<<<512, 256, 0, stream>>>(
            xbuf[l & 1],
            h16 + (size_t)l * Bsz * Hsz,
            wih16 + (size_t)l * 3 * Hsz * Hsz,
            whh16 + (size_t)l * 3 * Hsz * Hsz,
            b_ih + (size_t)l * 3 * Hsz,
            b_hh + (size_t)l * 3 * Hsz,
            hidden + (size_t)l * Bsz * Hsz,
            new_h + (size_t)l * Bsz * Hsz,
            xbuf[(l + 1) & 1]);
    }

    // 4) decoder: logits = h3 @ dec_w.T + dec_b   (h3 is in xbuf[0] after 4 layers)
    {
        int nx = OUTsz / 128;                          // 2
        int blocks = nx * (Bsz / 128);                 // 32
        gemm_dec<<<blocks, 256, 0, stream>>>(xbuf[Lsz & 1], wdec16, dec_b, logits,
                                             Bsz, OUTsz, Hsz, nx);
    }
}

// Round 9
// 177.370 us; speedup vs baseline: 4.2004x; 1.0262x over previous
//
#include <hip/hip_runtime.h>
#include <cstdint>
#include <cstddef>

// Problem constants (from reference): B=2048, IN=4, H=1024, L=4, OUT=256
#define Bsz   2048
#define INsz  4
#define Hsz   1024
#define Lsz   4
#define OUTsz 256

// ============================================================================
// RE-ANCHOR BUILD: byte-identical to the R4 kernel that PASSED at 182 µs
// (absmax 2.93e-3), with ONE inert edit: the duplicate/garbage i2h launch is
// removed (its output was fully overwritten by the correct launch).
// Record: counted-vmcnt loops failed 3x with identical absmax; 64x32 geometry
// failed under plain __syncthreads. Only this gru loop skeleton has passed
// for concat-K. Do not modify the gru loop without an isolated A/B.
// ============================================================================

typedef float f32x4 __attribute__((ext_vector_type(4)));
typedef short s16x8 __attribute__((ext_vector_type(8)));

typedef __attribute__((address_space(1))) void gvoid_t;  // global
typedef __attribute__((address_space(3))) void svoid_t;  // LDS

__device__ __forceinline__ unsigned short f2bf(float f) {
    union { float f; unsigned int u; } v; v.f = f;
    unsigned int r = 0x7FFFu + ((v.u >> 16) & 1u);
    return (unsigned short)((v.u + r) >> 16);
}

__device__ __forceinline__ float sigm(float x) {
    return 1.0f / (1.0f + __expf(-x));
}
__device__ __forceinline__ float tanh_fast(float x) {
    float a = __expf(-2.0f * fabsf(x));
    float t = (1.0f - a) / (1.0f + a);
    return copysignf(t, x);
}

// Inline-asm MFMA: signature-proof vs builtin bf16/short ambiguity.
__device__ __forceinline__ void mfma_bf16(f32x4& c, s16x8 a, s16x8 b) {
    asm("v_mfma_f32_16x16x32_bf16 %0, %1, %2, %0" : "+v"(c) : "v"(a), "v"(b));
}

// ---------------- fp32 -> bf16 cast (8 elems/thread) ----------------
__global__ void cast_bf16_kernel(const float* __restrict__ in,
                                 unsigned short* __restrict__ out, int n8) {
    int i = blockIdx.x * blockDim.x + threadIdx.x;
    if (i >= n8) return;
    const float4* p = (const float4*)in;
    float4 a = p[2 * i], b = p[2 * i + 1];
    union { unsigned short s[8]; uint4 u; } o;
    o.s[0] = f2bf(a.x); o.s[1] = f2bf(a.y); o.s[2] = f2bf(a.z); o.s[3] = f2bf(a.w);
    o.s[4] = f2bf(b.x); o.s[5] = f2bf(b.y); o.s[6] = f2bf(b.z); o.s[7] = f2bf(b.w);
    ((uint4*)out)[i] = o.u;
}

// ---------------- cast + gate-group reorder for GRU weights ----------------
// in: [L*3H, H] fp32, rows = l*3H + gate*H + j.
// out row' = l*3H + (j>>4)*48 + gate*16 + (j&15)  -> a block of 16 j-columns
// has its r,z,n gate rows contiguous (16 each). total8 = L*3H*H/8.
__global__ void cast_reorder_w(const float* __restrict__ in,
                               unsigned short* __restrict__ out, int total8) {
    int i = blockIdx.x * blockDim.x + threadIdx.x;
    if (i >= total8) return;
    int k8  = i & (Hsz / 8 - 1);          // 128 chunks per row
    int row = i >> 7;
    int l    = row / (3 * Hsz);
    int lrow = row - l * (3 * Hsz);
    int gate = lrow >> 10;
    int j    = lrow & (Hsz - 1);
    int rowp = l * (3 * Hsz) + ((j >> 4) * 48) + gate * 16 + (j & 15);
    const float4* p = (const float4*)(in + (size_t)row * Hsz + k8 * 8);
    float4 a = p[0], b = p[1];
    union { unsigned short s[8]; uint4 u; } o;
    o.s[0] = f2bf(a.x); o.s[1] = f2bf(a.y); o.s[2] = f2bf(a.z); o.s[3] = f2bf(a.w);
    o.s[4] = f2bf(b.x); o.s[5] = f2bf(b.y); o.s[6] = f2bf(b.z); o.s[7] = f2bf(b.w);
    *(uint4*)(out + (size_t)rowp * Hsz + k8 * 8) = o.u;
}

// ---------------- x0 = input @ i2h_w.T + i2h_b  (K=4, tiny) ----------------
__global__ void i2h_kernel(const float* __restrict__ inp, const float* __restrict__ w,
                           const float* __restrict__ b, unsigned short* __restrict__ xb) {
    int idx = blockIdx.x * blockDim.x + threadIdx.x;  // over B*H
    int j = idx & (Hsz - 1);
    int m = idx >> 10;
    float4 xi = ((const float4*)inp)[m];
    float4 wj = ((const float4*)w)[j];
    float v = xi.x * wj.x + xi.y * wj.y + xi.z * wj.z + xi.w * wj.w + b[j];
    xb[idx] = f2bf(v);
}

// ---------------- Fused GRU layer: concat-K dual GEMM + gate math ----------------
// Concat-K view: gates(r,z) = [x;h] @ [Wi_rz; Wh_rz]^T accumulated over K=2048
// (phase 0: A=x,B=Wi for k<1024; phase 1: A=h,B=Wh). n-gate keeps separate
// accumulators i_n (phase 0) and h_n (phase 1). Tile: 128 rows x 32 gate-cols
// (96 reordered W rows), 4 waves (2x2), wave = 64 rows x 16 cols, ni = gate.
// 1-deep pipelined 2-phase loop: STAGE(t+1, buf^1) issued before COMPUTE(t),
// one vmcnt(0)+barrier per tile. LDS double buffer 2x28KB -> 2 blk/CU.
// Staging: global_load_lds w=16, linear LDS dest, source pre-swizzled
// (chunk j of row r holds global chunk j^(r&7)) -> conflict-free ds_read_b128.
#define BUFSZ (224 * 64)   // (128 A-rows + 96 B-rows) * 64 k, elements
__global__ __launch_bounds__(256, 2)
void gru_fused(const unsigned short* __restrict__ x,   // [B,H] bf16 layer input
               const unsigned short* __restrict__ hb,  // [B,H] bf16 h_{t-1}
               const unsigned short* __restrict__ Wi,  // [3H,H] bf16 reordered
               const unsigned short* __restrict__ Wh,  // [3H,H] bf16 reordered
               const float* __restrict__ bih,          // [3H] original layout
               const float* __restrict__ bhh,          // [3H] original layout
               const float* __restrict__ hold,         // [B,H] fp32 h_{t-1}
               float* __restrict__ hout,               // [B,H] fp32 h'
               unsigned short* __restrict__ xout) {    // [B,H] bf16 h'
    // XCD-aware bijective swizzle (grid = 512, %8 == 0)
    const int bid = blockIdx.x;
    const int swz = (bid & 7) * 64 + (bid >> 3);
    const int my  = swz >> 5;        // row tile 0..15
    const int nxi = swz & 31;        // col tile 0..31

    __shared__ __align__(16) unsigned short lds[2 * BUFSZ];

    const int tid  = threadIdx.x;
    const int lane = tid & 63;
    const int w    = tid >> 6;
    const int wr   = w >> 1;         // wave row (0..1)
    const int wc   = w & 1;          // wave col / 16-col group (0..1)
    const long rowBase = (long)my * 128;
    const long colW    = (long)nxi * 96;   // reordered W row base

    f32x4 rz[4][2] = {};   // r,z gate sums (i+h), accumulated over all 32 steps
    f32x4 nin[4] = {};     // i_n (phase 0)
    f32x4 nhn[4] = {};     // h_n (phase 1)

    // Issue the 7 global_load_lds for K-tile tn into buffer buf.
    auto STAGE = [&](int tn, int buf) {
        const unsigned short* Ap = (tn < 16) ? x : hb;
        const unsigned short* Wp = (tn < 16) ? Wi : Wh;
        const long koff = (long)(tn & 15) * 64;
        unsigned short* la = lds + buf * BUFSZ;
        unsigned short* lb = la + 128 * 64;
        #pragma unroll
        for (int i = 0; i < 4; ++i) {            // A-tile: 1024 chunks
            const int cbase = (w * 4 + i) * 64;
            const int c = cbase + lane;
            const int r = c >> 3, jc = c & 7;
            const int js = (jc ^ (r & 7)) << 3;
            __builtin_amdgcn_global_load_lds(
                (gvoid_t*)(Ap + (rowBase + r) * (long)Hsz + koff + js),
                (svoid_t*)(la + cbase * 8), 16, 0, 0);
        }
        #pragma unroll
        for (int i = 0; i < 3; ++i) {            // B-tile: 768 chunks
            const int cbase = (w * 3 + i) * 64;
            const int c = cbase + lane;
            const int r = c >> 3, jc = c & 7;
            const int js = (jc ^ (r & 7)) << 3;
            __builtin_amdgcn_global_load_lds(
                (gvoid_t*)(Wp + (colW + r) * (long)Hsz + koff + js),
                (svoid_t*)(lb + cbase * 8), 16, 0, 0);
        }
    };

    auto COMPUTE = [&](int t) {
        const unsigned short* la = lds + (t & 1) * BUFSZ;
        const unsigned short* lb = la + 128 * 64;
        const bool ph0 = (t < 16);               // wave-uniform
        #pragma unroll
        for (int kk = 0; kk < 2; ++kk) {
            s16x8 av[4], bv[3];
            const int jk = kk * 4 + (lane >> 4);
            #pragma unroll
            for (int mi = 0; mi < 4; ++mi) {
                int r = wr * 64 + mi * 16 + (lane & 15);
                av[mi] = *(const s16x8*)&la[r * 64 + ((jk ^ (r & 7)) << 3)];
            }
            #pragma unroll
            for (int ni = 0; ni < 3; ++ni) {
                int r = wc * 48 + ni * 16 + (lane & 15);
                bv[ni] = *(const s16x8*)&lb[r * 64 + ((jk ^ (r & 7)) << 3)];
            }
            __builtin_amdgcn_s_setprio(1);
            #pragma unroll
            for (int mi = 0; mi < 4; ++mi) {
                mfma_bf16(rz[mi][0], av[mi], bv[0]);
                mfma_bf16(rz[mi][1], av[mi], bv[1]);
            }
            if (ph0) {
                #pragma unroll
                for (int mi = 0; mi < 4; ++mi) mfma_bf16(nin[mi], av[mi], bv[2]);
            } else {
                #pragma unroll
                for (int mi = 0; mi < 4; ++mi) mfma_bf16(nhn[mi], av[mi], bv[2]);
            }
            __builtin_amdgcn_s_setprio(0);
        }
    };

    STAGE(0, 0);
    __syncthreads();                  // vmcnt(0) drain + barrier: tile 0 ready
    #pragma unroll 2
    for (int t = 0; t < 31; ++t) {
        STAGE(t + 1, (t + 1) & 1);    // overlaps with COMPUTE(t)
        COMPUTE(t);
        __syncthreads();              // drains t+1 loads; protects buf reuse
    }
    COMPUTE(31);

    // Guard MFMA-write -> VALU-read hazard (inline-asm MFMA bypasses the
    // compiler's hazard recognizer).
    asm volatile("s_nop 7\n\ts_nop 7");

    // ---- GRU epilogue (all per-lane, no cross-lane) ----
    const int j = nxi * 32 + wc * 16 + (lane & 15);   // gate column 0..1023
    const float br = bih[j]           + bhh[j];
    const float bz = bih[Hsz + j]     + bhh[Hsz + j];
    const float bin = bih[2 * Hsz + j];
    const float bhn = bhh[2 * Hsz + j];

    #pragma unroll
    for (int mi = 0; mi < 4; ++mi) {
        #pragma unroll
        for (int q = 0; q < 4; ++q) {
            long row = rowBase + wr * 64 + mi * 16 + ((lane >> 4) << 2) + q;
            float r = sigm(rz[mi][0][q] + br);
            float z = sigm(rz[mi][1][q] + bz);
            float n = tanh_fast(nin[mi][q] + bin + r * (nhn[mi][q] + bhn));
            float hv = hold[row * Hsz + j];
            float o  = (1.0f - z) * n + z * hv;
            hout[row * Hsz + j] = o;
            xout[row * Hsz + j] = f2bf(o);
        }
    }
}

// ---------------- decoder GEMM: C = A @ W^T + b (128x128 tile, m97 structure) ----------------
__global__ __launch_bounds__(256)
void gemm_dec(const unsigned short* __restrict__ A, const unsigned short* __restrict__ Bw,
              const float* __restrict__ bias, float* __restrict__ C,
              int M, int N, int K, int nx) {
    const int nwg = gridDim.x;
    const int cpx = nwg >> 3;
    const int bid = blockIdx.x;
    const int swz = (bid & 7) * cpx + (bid >> 3);
    const int my  = swz / nx;
    const int nxi = swz - my * nx;

    __shared__ __align__(16) unsigned short lA[128 * 64];
    __shared__ __align__(16) unsigned short lB[128 * 64];

    const int tid  = threadIdx.x;
    const int lane = tid & 63;
    const int w    = tid >> 6;
    const int wr   = w >> 1;
    const int wc   = w & 1;
    const long rowBase = (long)my * 128;
    const long colBase = (long)nxi * 128;

    f32x4 acc[4][4] = {};

    for (int k0 = 0; k0 < K; k0 += 64) {
        __syncthreads();
        #pragma unroll
        for (int i = 0; i < 4; ++i) {
            const int cbase = (w * 4 + i) * 64;
            const int c = cbase + lane;
            const int r = c >> 3, jc = c & 7;
            const int js = (jc ^ (r & 7)) << 3;
            __builtin_amdgcn_global_load_lds((gvoid_t*)(A  + (rowBase + r) * (long)K + k0 + js),
                                             (svoid_t*)(lA + cbase * 8), 16, 0, 0);
            __builtin_amdgcn_global_load_lds((gvoid_t*)(Bw + (colBase + r) * (long)K + k0 + js),
                                             (svoid_t*)(lB + cbase * 8), 16, 0, 0);
        }
        __syncthreads();

        #pragma unroll
        for (int kk = 0; kk < 2; ++kk) {
            s16x8 af[4], bf[4];
            const int jk = kk * 4 + (lane >> 4);
            #pragma unroll
            for (int mi = 0; mi < 4; ++mi) {
                int r = wr * 64 + mi * 16 + (lane & 15);
                af[mi] = *(const s16x8*)&lA[r * 64 + ((jk ^ (r & 7)) << 3)];
            }
            #pragma unroll
            for (int ni = 0; ni < 4; ++ni) {
                int r = wc * 64 + ni * 16 + (lane & 15);
                bf[ni] = *(const s16x8*)&lB[r * 64 + ((jk ^ (r & 7)) << 3)];
            }
            #pragma unroll
            for (int mi = 0; mi < 4; ++mi)
                #pragma unroll
                for (int ni = 0; ni < 4; ++ni)
                    mfma_bf16(acc[mi][ni], af[mi], bf[ni]);
        }
    }

    asm volatile("s_nop 7\n\ts_nop 7");

    #pragma unroll
    for (int mi = 0; mi < 4; ++mi) {
        #pragma unroll
        for (int ni = 0; ni < 4; ++ni) {
            long col = colBase + wc * 64 + ni * 16 + (lane & 15);
            float bv = bias[col];
            #pragma unroll
            for (int q = 0; q < 4; ++q) {
                long row = rowBase + wr * 64 + mi * 16 + (lane >> 4) * 4 + q;
                C[row * (long)N + col] = acc[mi][ni][q] + bv;
            }
        }
    }
}

extern "C" void kernel_launch(void* const* d_in, const int* in_sizes, int n_in,
                              void* d_out, int out_size, void* d_ws, size_t ws_size,
                              hipStream_t stream) {
    const float* input  = (const float*)d_in[0];
    const float* hidden = (const float*)d_in[1];
    const float* i2h_w  = (const float*)d_in[2];
    const float* i2h_b  = (const float*)d_in[3];
    const float* w_ih   = (const float*)d_in[4];
    const float* w_hh   = (const float*)d_in[5];
    const float* b_ih   = (const float*)d_in[6];
    const float* b_hh   = (const float*)d_in[7];
    const float* dec_w  = (const float*)d_in[8];
    const float* dec_b  = (const float*)d_in[9];

    float* logits = (float*)d_out;                       // [B, OUT]
    float* new_h  = (float*)d_out + (size_t)Bsz * OUTsz; // [L, B, H]

    // Workspace layout (~76 MB)
    char* p = (char*)d_ws;
    unsigned short* wih16  = (unsigned short*)p; p += (size_t)Lsz * 3 * Hsz * Hsz * 2;
    unsigned short* whh16  = (unsigned short*)p; p += (size_t)Lsz * 3 * Hsz * Hsz * 2;
    unsigned short* wdec16 = (unsigned short*)p; p += (size_t)OUTsz * Hsz * 2;
    unsigned short* h16    = (unsigned short*)p; p += (size_t)Lsz * Bsz * Hsz * 2;
    unsigned short* xb0    = (unsigned short*)p; p += (size_t)Bsz * Hsz * 2;
    unsigned short* xb1    = (unsigned short*)p; p += (size_t)Bsz * Hsz * 2;
    unsigned short* xbuf[2] = { xb0, xb1 };

    // 1) casts (+ gate-group reorder for GRU weights)
    {
        int n8 = Lsz * 3 * Hsz * Hsz / 8;
        cast_reorder_w<<<(n8 + 255) / 256, 256, 0, stream>>>(w_ih, wih16, n8);
        cast_reorder_w<<<(n8 + 255) / 256, 256, 0, stream>>>(w_hh, whh16, n8);
    }
    {
        int n8 = OUTsz * Hsz / 8;
        cast_bf16_kernel<<<(n8 + 255) / 256, 256, 0, stream>>>(dec_w, wdec16, n8);
    }
    {
        int n8 = Lsz * Bsz * Hsz / 8;
        cast_bf16_kernel<<<(n8 + 255) / 256, 256, 0, stream>>>(hidden, h16, n8);
    }

    // 2) i2h projection -> xb0 (bf16)  [single correct launch; R4's garbage
    //    duplicate removed — it was fully overwritten by this one]
    i2h_kernel<<<(Bsz * Hsz) / 256, 256, 0, stream>>>(input, i2h_w, i2h_b, xb0);

    // 3) fused GRU layers (one launch each)
    for (int l = 0; l < Lsz; ++l) {
        gru_fused<<<512, 256, 0, stream>>>(
            xbuf[l & 1],
            h16 + (size_t)l * Bsz * Hsz,
            wih16 + (size_t)l * 3 * Hsz * Hsz,
            whh16 + (size_t)l * 3 * Hsz * Hsz,
            b_ih + (size_t)l * 3 * Hsz,
            b_hh + (size_t)l * 3 * Hsz,
            hidden + (size_t)l * Bsz * Hsz,
            new_h + (size_t)l * Bsz * Hsz,
            xbuf[(l + 1) & 1]);
    }

    // 4) decoder: logits = h3 @ dec_w.T + dec_b   (h3 is in xbuf[0] after 4 layers)
    {
        int nx = OUTsz / 128;                          // 2
        int blocks = nx * (Bsz / 128);                 // 32
        gemm_dec<<<blocks, 256, 0, stream>>>(xbuf[Lsz & 1], wdec16, dec_b, logits,
                                             Bsz, OUTsz, Hsz, nx);
    }
}

// Round 11
// 172.820 us; speedup vs baseline: 4.3110x; 1.0263x over previous
//
#include <hip/hip_runtime.h>
#include <cstdint>
#include <cstddef>

// Problem constants (from reference): B=2048, IN=4, H=1024, L=4, OUT=256
#define Bsz   2048
#define INsz  4
#define Hsz   1024
#define Lsz   4
#define OUTsz 256

// ============================================================================
// ANCHOR: R9 passed (177 µs, absmax 2.93e-3). Record: FIVE structurally-new
// gru kernels failed numerically (R5-R8, R10) despite clean audits. gru_fused
// below is BYTE-IDENTICAL to R9 except the block->tile swizzle (arithmetic-
// neutral bijection: 4 colTiles x 16 rowTiles per XCD -> W panel 768 KB =
// L2-resident, loads land from L2 ~200cyc instead of L3/HBM 400-900cyc at
// every __syncthreads drain). Casts merged per the R4-proven grid.y=2 form.
// DO NOT restructure the gru loop/staging/fragments.
// ============================================================================

typedef float f32x4 __attribute__((ext_vector_type(4)));
typedef short s16x8 __attribute__((ext_vector_type(8)));

typedef __attribute__((address_space(1))) void gvoid_t;  // global
typedef __attribute__((address_space(3))) void svoid_t;  // LDS

__device__ __forceinline__ unsigned short f2bf(float f) {
    union { float f; unsigned int u; } v; v.f = f;
    unsigned int r = 0x7FFFu + ((v.u >> 16) & 1u);
    return (unsigned short)((v.u + r) >> 16);
}

__device__ __forceinline__ float sigm(float x) {
    return 1.0f / (1.0f + __expf(-x));
}
__device__ __forceinline__ float tanh_fast(float x) {
    float a = __expf(-2.0f * fabsf(x));
    float t = (1.0f - a) / (1.0f + a);
    return copysignf(t, x);
}

// Inline-asm MFMA: signature-proof vs builtin bf16/short ambiguity.
__device__ __forceinline__ void mfma_bf16(f32x4& c, s16x8 a, s16x8 b) {
    asm("v_mfma_f32_16x16x32_bf16 %0, %1, %2, %0" : "+v"(c) : "v"(a), "v"(b));
}

// ---------------- fp32 -> bf16 cast (8 elems/thread) ----------------
__global__ void cast_bf16_kernel(const float* __restrict__ in,
                                 unsigned short* __restrict__ out, int n8) {
    int i = blockIdx.x * blockDim.x + threadIdx.x;
    if (i >= n8) return;
    const float4* p = (const float4*)in;
    float4 a = p[2 * i], b = p[2 * i + 1];
    union { unsigned short s[8]; uint4 u; } o;
    o.s[0] = f2bf(a.x); o.s[1] = f2bf(a.y); o.s[2] = f2bf(a.z); o.s[3] = f2bf(a.w);
    o.s[4] = f2bf(b.x); o.s[5] = f2bf(b.y); o.s[6] = f2bf(b.z); o.s[7] = f2bf(b.w);
    ((uint4*)out)[i] = o.u;
}

// ---------------- cast + gate-group reorder for GRU weights ----------------
// in: [L*3H, H] fp32, rows = l*3H + gate*H + j.
// out row' = l*3H + (j>>4)*48 + gate*16 + (j&15)  -> a block of 16 j-columns
// has its r,z,n gate rows contiguous (16 each). total8 = L*3H*H/8.
// blockIdx.y selects (in0->out0) or (in1->out1): one launch for both weights.
// (This exact merged kernel ran in the PASSING R4 build.)
__global__ void cast_reorder_w(const float* __restrict__ in0,
                               unsigned short* __restrict__ out0,
                               const float* __restrict__ in1,
                               unsigned short* __restrict__ out1, int total8) {
    int i = blockIdx.x * blockDim.x + threadIdx.x;
    if (i >= total8) return;
    const float* in      = blockIdx.y ? in1 : in0;
    unsigned short* out  = blockIdx.y ? out1 : out0;
    int k8  = i & (Hsz / 8 - 1);          // 128 chunks per row
    int row = i >> 7;
    int l    = row / (3 * Hsz);
    int lrow = row - l * (3 * Hsz);
    int gate = lrow >> 10;
    int j    = lrow & (Hsz - 1);
    int rowp = l * (3 * Hsz) + ((j >> 4) * 48) + gate * 16 + (j & 15);
    const float4* p = (const float4*)(in + (size_t)row * Hsz + k8 * 8);
    float4 a = p[0], b = p[1];
    union { unsigned short s[8]; uint4 u; } o;
    o.s[0] = f2bf(a.x); o.s[1] = f2bf(a.y); o.s[2] = f2bf(a.z); o.s[3] = f2bf(a.w);
    o.s[4] = f2bf(b.x); o.s[5] = f2bf(b.y); o.s[6] = f2bf(b.z); o.s[7] = f2bf(b.w);
    *(uint4*)(out + (size_t)rowp * Hsz + k8 * 8) = o.u;
}

// ---------------- x0 = input @ i2h_w.T + i2h_b  (K=4, tiny) ----------------
__global__ void i2h_kernel(const float* __restrict__ inp, const float* __restrict__ w,
                           const float* __restrict__ b, unsigned short* __restrict__ xb) {
    int idx = blockIdx.x * blockDim.x + threadIdx.x;  // over B*H
    int j = idx & (Hsz - 1);
    int m = idx >> 10;
    float4 xi = ((const float4*)inp)[m];
    float4 wj = ((const float4*)w)[j];
    float v = xi.x * wj.x + xi.y * wj.y + xi.z * wj.z + xi.w * wj.w + b[j];
    xb[idx] = f2bf(v);
}

// ---------------- Fused GRU layer: concat-K dual GEMM + gate math ----------------
// Concat-K view: gates(r,z) = [x;h] @ [Wi_rz; Wh_rz]^T accumulated over K=2048
// (phase 0: A=x,B=Wi for k<1024; phase 1: A=h,B=Wh). n-gate keeps separate
// accumulators i_n (phase 0) and h_n (phase 1). Tile: 128 rows x 32 gate-cols
// (96 reordered W rows), 4 waves (2x2), wave = 64 rows x 16 cols, ni = gate.
// 1-deep pipelined 2-phase loop: STAGE(t+1, buf^1) issued before COMPUTE(t),
// one vmcnt(0)+barrier per tile. LDS double buffer 2x28KB -> 2 blk/CU.
// Staging: global_load_lds w=16, linear LDS dest, source pre-swizzled
// (chunk j of row r holds global chunk j^(r&7)) -> conflict-free ds_read_b128.
#define BUFSZ (224 * 64)   // (128 A-rows + 96 B-rows) * 64 k, elements
__global__ __launch_bounds__(256, 2)
void gru_fused(const unsigned short* __restrict__ x,   // [B,H] bf16 layer input
               const unsigned short* __restrict__ hb,  // [B,H] bf16 h_{t-1}
               const unsigned short* __restrict__ Wi,  // [3H,H] bf16 reordered
               const unsigned short* __restrict__ Wh,  // [3H,H] bf16 reordered
               const float* __restrict__ bih,          // [3H] original layout
               const float* __restrict__ bhh,          // [3H] original layout
               const float* __restrict__ hold,         // [B,H] fp32 h_{t-1}
               float* __restrict__ hout,               // [B,H] fp32 h'
               unsigned short* __restrict__ xout) {    // [B,H] bf16 h'
    // XCD-aware bijective swizzle (grid = 512, %8 == 0), L2-residency grouped:
    // per XCD (bid&7): colTiles [xcd*4, xcd*4+4) x ALL 16 rowTiles (64 blocks,
    // all co-resident at 2 blk/CU x 32 CU). W working set/XCD = 4 x 192 KB =
    // 768 KB -> L2-resident; A slabs get their 4x colTile reuse from L2 too.
    const int bid = blockIdx.x;
    const int ii  = bid >> 3;               // 0..63 within XCD
    const int my  = ii & 15;                // row tile 0..15
    const int nxi = (bid & 7) * 4 + (ii >> 4);  // col tile 0..31

    __shared__ __align__(16) unsigned short lds[2 * BUFSZ];

    const int tid  = threadIdx.x;
    const int lane = tid & 63;
    const int w    = tid >> 6;
    const int wr   = w >> 1;         // wave row (0..1)
    const int wc   = w & 1;          // wave col / 16-col group (0..1)
    const long rowBase = (long)my * 128;
    const long colW    = (long)nxi * 96;   // reordered W row base

    f32x4 rz[4][2] = {};   // r,z gate sums (i+h), accumulated over all 32 steps
    f32x4 nin[4] = {};     // i_n (phase 0)
    f32x4 nhn[4] = {};     // h_n (phase 1)

    // Issue the 7 global_load_lds for K-tile tn into buffer buf.
    auto STAGE = [&](int tn, int buf) {
        const unsigned short* Ap = (tn < 16) ? x : hb;
        const unsigned short* Wp = (tn < 16) ? Wi : Wh;
        const long koff = (long)(tn & 15) * 64;
        unsigned short* la = lds + buf * BUFSZ;
        unsigned short* lb = la + 128 * 64;
        #pragma unroll
        for (int i = 0; i < 4; ++i) {            // A-tile: 1024 chunks
            const int cbase = (w * 4 + i) * 64;
            const int c = cbase + lane;
            const int r = c >> 3, jc = c & 7;
            const int js = (jc ^ (r & 7)) << 3;
            __builtin_amdgcn_global_load_lds(
                (gvoid_t*)(Ap + (rowBase + r) * (long)Hsz + koff + js),
                (svoid_t*)(la + cbase * 8), 16, 0, 0);
        }
        #pragma unroll
        for (int i = 0; i < 3; ++i) {            // B-tile: 768 chunks
            const int cbase = (w * 3 + i) * 64;
            const int c = cbase + lane;
            const int r = c >> 3, jc = c & 7;
            const int js = (jc ^ (r & 7)) << 3;
            __builtin_amdgcn_global_load_lds(
                (gvoid_t*)(Wp + (colW + r) * (long)Hsz + koff + js),
                (svoid_t*)(lb + cbase * 8), 16, 0, 0);
        }
    };

    auto COMPUTE = [&](int t) {
        const unsigned short* la = lds + (t & 1) * BUFSZ;
        const unsigned short* lb = la + 128 * 64;
        const bool ph0 = (t < 16);               // wave-uniform
        #pragma unroll
        for (int kk = 0; kk < 2; ++kk) {
            s16x8 av[4], bv[3];
            const int jk = kk * 4 + (lane >> 4);
            #pragma unroll
            for (int mi = 0; mi < 4; ++mi) {
                int r = wr * 64 + mi * 16 + (lane & 15);
                av[mi] = *(const s16x8*)&la[r * 64 + ((jk ^ (r & 7)) << 3)];
            }
            #pragma unroll
            for (int ni = 0; ni < 3; ++ni) {
                int r = wc * 48 + ni * 16 + (lane & 15);
                bv[ni] = *(const s16x8*)&lb[r * 64 + ((jk ^ (r & 7)) << 3)];
            }
            __builtin_amdgcn_s_setprio(1);
            #pragma unroll
            for (int mi = 0; mi < 4; ++mi) {
                mfma_bf16(rz[mi][0], av[mi], bv[0]);
                mfma_bf16(rz[mi][1], av[mi], bv[1]);
            }
            if (ph0) {
                #pragma unroll
                for (int mi = 0; mi < 4; ++mi) mfma_bf16(nin[mi], av[mi], bv[2]);
            } else {
                #pragma unroll
                for (int mi = 0; mi < 4; ++mi) mfma_bf16(nhn[mi], av[mi], bv[2]);
            }
            __builtin_amdgcn_s_setprio(0);
        }
    };

    STAGE(0, 0);
    __syncthreads();                  // vmcnt(0) drain + barrier: tile 0 ready
    #pragma unroll 2
    for (int t = 0; t < 31; ++t) {
        STAGE(t + 1, (t + 1) & 1);    // overlaps with COMPUTE(t)
        COMPUTE(t);
        __syncthreads();              // drains t+1 loads; protects buf reuse
    }
    COMPUTE(31);

    // Guard MFMA-write -> VALU-read hazard (inline-asm MFMA bypasses the
    // compiler's hazard recognizer).
    asm volatile("s_nop 7\n\ts_nop 7");

    // ---- GRU epilogue (all per-lane, no cross-lane) ----
    const int j = nxi * 32 + wc * 16 + (lane & 15);   // gate column 0..1023
    const float br = bih[j]           + bhh[j];
    const float bz = bih[Hsz + j]     + bhh[Hsz + j];
    const float bin = bih[2 * Hsz + j];
    const float bhn = bhh[2 * Hsz + j];

    #pragma unroll
    for (int mi = 0; mi < 4; ++mi) {
        #pragma unroll
        for (int q = 0; q < 4; ++q) {
            long row = rowBase + wr * 64 + mi * 16 + ((lane >> 4) << 2) + q;
            float r = sigm(rz[mi][0][q] + br);
            float z = sigm(rz[mi][1][q] + bz);
            float n = tanh_fast(nin[mi][q] + bin + r * (nhn[mi][q] + bhn));
            float hv = hold[row * Hsz + j];
            float o  = (1.0f - z) * n + z * hv;
            hout[row * Hsz + j] = o;
            xout[row * Hsz + j] = f2bf(o);
        }
    }
}

// ---------------- decoder GEMM: C = A @ W^T + b (128x128 tile, m97 structure) ----------------
__global__ __launch_bounds__(256)
void gemm_dec(const unsigned short* __restrict__ A, const unsigned short* __restrict__ Bw,
              const float* __restrict__ bias, float* __restrict__ C,
              int M, int N, int K, int nx) {
    const int nwg = gridDim.x;
    const int cpx = nwg >> 3;
    const int bid = blockIdx.x;
    const int swz = (bid & 7) * cpx + (bid >> 3);
    const int my  = swz / nx;
    const int nxi = swz - my * nx;

    __shared__ __align__(16) unsigned short lA[128 * 64];
    __shared__ __align__(16) unsigned short lB[128 * 64];

    const int tid  = threadIdx.x;
    const int lane = tid & 63;
    const int w    = tid >> 6;
    const int wr   = w >> 1;
    const int wc   = w & 1;
    const long rowBase = (long)my * 128;
    const long colBase = (long)nxi * 128;

    f32x4 acc[4][4] = {};

    for (int k0 = 0; k0 < K; k0 += 64) {
        __syncthreads();
        #pragma unroll
        for (int i = 0; i < 4; ++i) {
            const int cbase = (w * 4 + i) * 64;
            const int c = cbase + lane;
            const int r = c >> 3, jc = c & 7;
            const int js = (jc ^ (r & 7)) << 3;
            __builtin_amdgcn_global_load_lds((gvoid_t*)(A  + (rowBase + r) * (long)K + k0 + js),
                                             (svoid_t*)(lA + cbase * 8), 16, 0, 0);
            __builtin_amdgcn_global_load_lds((gvoid_t*)(Bw + (colBase + r) * (long)K + k0 + js),
                                             (svoid_t*)(lB + cbase * 8), 16, 0, 0);
        }
        __syncthreads();

        #pragma unroll
        for (int kk = 0; kk < 2; ++kk) {
            s16x8 af[4], bf[4];
            const int jk = kk * 4 + (lane >> 4);
            #pragma unroll
            for (int mi = 0; mi < 4; ++mi) {
                int r = wr * 64 + mi * 16 + (lane & 15);
                af[mi] = *(const s16x8*)&lA[r * 64 + ((jk ^ (r & 7)) << 3)];
            }
            #pragma unroll
            for (int ni = 0; ni < 4; ++ni) {
                int r = wc * 64 + ni * 16 + (lane & 15);
                bf[ni] = *(const s16x8*)&lB[r * 64 + ((jk ^ (r & 7)) << 3)];
            }
            #pragma unroll
            for (int mi = 0; mi < 4; ++mi)
                #pragma unroll
                for (int ni = 0; ni < 4; ++ni)
                    mfma_bf16(acc[mi][ni], af[mi], bf[ni]);
        }
    }

    asm volatile("s_nop 7\n\ts_nop 7");

    #pragma unroll
    for (int mi = 0; mi < 4; ++mi) {
        #pragma unroll
        for (int ni = 0; ni < 4; ++ni) {
            long col = colBase + wc * 64 + ni * 16 + (lane & 15);
            float bv = bias[col];
            #pragma unroll
            for (int q = 0; q < 4; ++q) {
                long row = rowBase + wr * 64 + mi * 16 + (lane >> 4) * 4 + q;
                C[row * (long)N + col] = acc[mi][ni][q] + bv;
            }
        }
    }
}

extern "C" void kernel_launch(void* const* d_in, const int* in_sizes, int n_in,
                              void* d_out, int out_size, void* d_ws, size_t ws_size,
                              hipStream_t stream) {
    const float* input  = (const float*)d_in[0];
    const float* hidden = (const float*)d_in[1];
    const float* i2h_w  = (const float*)d_in[2];
    const float* i2h_b  = (const float*)d_in[3];
    const float* w_ih   = (const float*)d_in[4];
    const float* w_hh   = (const float*)d_in[5];
    const float* b_ih   = (const float*)d_in[6];
    const float* b_hh   = (const float*)d_in[7];
    const float* dec_w  = (const float*)d_in[8];
    const float* dec_b  = (const float*)d_in[9];

    float* logits = (float*)d_out;                       // [B, OUT]
    float* new_h  = (float*)d_out + (size_t)Bsz * OUTsz; // [L, B, H]

    // Workspace layout (~76 MB)
    char* p = (char*)d_ws;
    unsigned short* wih16  = (unsigned short*)p; p += (size_t)Lsz * 3 * Hsz * Hsz * 2;
    unsigned short* whh16  = (unsigned short*)p; p += (size_t)Lsz * 3 * Hsz * Hsz * 2;
    unsigned short* wdec16 = (unsigned short*)p; p += (size_t)OUTsz * Hsz * 2;
    unsigned short* h16    = (unsigned short*)p; p += (size_t)Lsz * Bsz * Hsz * 2;
    unsigned short* xb0    = (unsigned short*)p; p += (size_t)Bsz * Hsz * 2;
    unsigned short* xb1    = (unsigned short*)p; p += (size_t)Bsz * Hsz * 2;
    unsigned short* xbuf[2] = { xb0, xb1 };

    // 1) casts (+ gate-group reorder for GRU weights; merged R4-proven launch)
    {
        int n8 = Lsz * 3 * Hsz * Hsz / 8;
        dim3 grid((n8 + 255) / 256, 2);
        cast_reorder_w<<<grid, 256, 0, stream>>>(w_ih, wih16, w_hh, whh16, n8);
    }
    {
        int n8 = OUTsz * Hsz / 8;
        cast_bf16_kernel<<<(n8 + 255) / 256, 256, 0, stream>>>(dec_w, wdec16, n8);
    }
    {
        int n8 = Lsz * Bsz * Hsz / 8;
        cast_bf16_kernel<<<(n8 + 255) / 256, 256, 0, stream>>>(hidden, h16, n8);
    }

    // 2) i2h projection -> xb0 (bf16)
    i2h_kernel<<<(Bsz * Hsz) / 256, 256, 0, stream>>>(input, i2h_w, i2h_b, xb0);

    // 3) fused GRU layers (one launch each)
    for (int l = 0; l < Lsz; ++l) {
        gru_fused<<<512, 256, 0, stream>>>(
            xbuf[l & 1],
            h16 + (size_t)l * Bsz * Hsz,
            wih16 + (size_t)l * 3 * Hsz * Hsz,
            whh16 + (size_t)l * 3 * Hsz * Hsz,
            b_ih + (size_t)l * 3 * Hsz,
            b_hh + (size_t)l * 3 * Hsz,
            hidden + (size_t)l * Bsz * Hsz,
            new_h + (size_t)l * Bsz * Hsz,
            xbuf[(l + 1) & 1]);
    }

    // 4) decoder: logits = h3 @ dec_w.T + dec_b   (h3 is in xbuf[0] after 4 layers)
    {
        int nx = OUTsz / 128;                          // 2
        int blocks = nx * (Bsz / 128);                 // 32
        gemm_dec<<<blocks, 256, 0, stream>>>(xbuf[Lsz & 1], wdec16, dec_b, logits,
                                             Bsz, OUTsz, Hsz, nx);
    }
}

// Round 12
// 168.135 us; speedup vs baseline: 4.4311x; 1.0279x over previous
//
#include <hip/hip_runtime.h>
#include <cstdint>
#include <cstddef>

// Problem constants (from reference): B=2048, IN=4, H=1024, L=4, OUT=256
#define Bsz   2048
#define INsz  4
#define Hsz   1024
#define Lsz   4
#define OUTsz 256

// ============================================================================
// ANCHOR: R11 passed (172.8 µs, absmax 2.93e-3). Record: FIVE structural gru
// redesigns (R5-R8, R10) failed numerically with deterministic wrong values
// despite clean audits -> gru_fused and gemm_dec are BYTE-FROZEN from R11.
// This round's only change: the 5 pre-GRU elementwise kernels are merged into
// ONE `prework` launch (block-range dispatch, bodies verbatim, block-uniform
// branch; every region an exact multiple of 256 threads). Arithmetic-identical.
// ============================================================================

typedef float f32x4 __attribute__((ext_vector_type(4)));
typedef short s16x8 __attribute__((ext_vector_type(8)));

typedef __attribute__((address_space(1))) void gvoid_t;  // global
typedef __attribute__((address_space(3))) void svoid_t;  // LDS

__device__ __forceinline__ unsigned short f2bf(float f) {
    union { float f; unsigned int u; } v; v.f = f;
    unsigned int r = 0x7FFFu + ((v.u >> 16) & 1u);
    return (unsigned short)((v.u + r) >> 16);
}

__device__ __forceinline__ float sigm(float x) {
    return 1.0f / (1.0f + __expf(-x));
}
__device__ __forceinline__ float tanh_fast(float x) {
    float a = __expf(-2.0f * fabsf(x));
    float t = (1.0f - a) / (1.0f + a);
    return copysignf(t, x);
}

// Inline-asm MFMA: signature-proof vs builtin bf16/short ambiguity.
__device__ __forceinline__ void mfma_bf16(f32x4& c, s16x8 a, s16x8 b) {
    asm("v_mfma_f32_16x16x32_bf16 %0, %1, %2, %0" : "+v"(c) : "v"(a), "v"(b));
}

// ---------------- pre-work bodies (verbatim from the proven kernels) ----------------
__device__ __forceinline__ void body_cast8(const float* __restrict__ in,
                                           unsigned short* __restrict__ out, int i) {
    const float4* p = (const float4*)in;
    float4 a = p[2 * i], b = p[2 * i + 1];
    union { unsigned short s[8]; uint4 u; } o;
    o.s[0] = f2bf(a.x); o.s[1] = f2bf(a.y); o.s[2] = f2bf(a.z); o.s[3] = f2bf(a.w);
    o.s[4] = f2bf(b.x); o.s[5] = f2bf(b.y); o.s[6] = f2bf(b.z); o.s[7] = f2bf(b.w);
    ((uint4*)out)[i] = o.u;
}

// weight gate-group reorder: out row' = l*3H + (j>>4)*48 + gate*16 + (j&15)
__device__ __forceinline__ void body_reorder(const float* __restrict__ in,
                                             unsigned short* __restrict__ out, int i) {
    int k8  = i & (Hsz / 8 - 1);          // 128 chunks per row
    int row = i >> 7;
    int l    = row / (3 * Hsz);
    int lrow = row - l * (3 * Hsz);
    int gate = lrow >> 10;
    int j    = lrow & (Hsz - 1);
    int rowp = l * (3 * Hsz) + ((j >> 4) * 48) + gate * 16 + (j & 15);
    const float4* p = (const float4*)(in + (size_t)row * Hsz + k8 * 8);
    float4 a = p[0], b = p[1];
    union { unsigned short s[8]; uint4 u; } o;
    o.s[0] = f2bf(a.x); o.s[1] = f2bf(a.y); o.s[2] = f2bf(a.z); o.s[3] = f2bf(a.w);
    o.s[4] = f2bf(b.x); o.s[5] = f2bf(b.y); o.s[6] = f2bf(b.z); o.s[7] = f2bf(b.w);
    *(uint4*)(out + (size_t)rowp * Hsz + k8 * 8) = o.u;
}

__device__ __forceinline__ void body_i2h(const float* __restrict__ inp,
                                         const float* __restrict__ w,
                                         const float* __restrict__ b,
                                         unsigned short* __restrict__ xb, int idx) {
    int j = idx & (Hsz - 1);
    int m = idx >> 10;
    float4 xi = ((const float4*)inp)[m];
    float4 wj = ((const float4*)w)[j];
    float v = xi.x * wj.x + xi.y * wj.y + xi.z * wj.z + xi.w * wj.w + b[j];
    xb[idx] = f2bf(v);
}

// ---------------- ONE merged pre-work launch ----------------
// Block ranges (all exact multiples of 256 threads; branch block-uniform):
//   [0,6144)       w_ih reorder   (n8w = 1,572,864)
//   [6144,12288)   w_hh reorder
//   [12288,12416)  dec_w cast     (n8d = 32,768)
//   [12416,16512)  hidden cast    (n8h = 1,048,576)
//   [16512,24704)  i2h            (B*H = 2,097,152 threads)
__global__ void prework(const float* __restrict__ w_ih, unsigned short* __restrict__ wih16,
                        const float* __restrict__ w_hh, unsigned short* __restrict__ whh16,
                        const float* __restrict__ dec_w, unsigned short* __restrict__ wdec16,
                        const float* __restrict__ hidden, unsigned short* __restrict__ h16,
                        const float* __restrict__ input, const float* __restrict__ i2h_w,
                        const float* __restrict__ i2h_b, unsigned short* __restrict__ xb0) {
    const int b   = blockIdx.x;
    const int tid = threadIdx.x;
    if (b < 6144) {
        body_reorder(w_ih, wih16, b * 256 + tid);
    } else if (b < 12288) {
        body_reorder(w_hh, whh16, (b - 6144) * 256 + tid);
    } else if (b < 12416) {
        body_cast8(dec_w, wdec16, (b - 12288) * 256 + tid);
    } else if (b < 16512) {
        body_cast8(hidden, h16, (b - 12416) * 256 + tid);
    } else {
        body_i2h(input, i2h_w, i2h_b, xb0, (b - 16512) * 256 + tid);
    }
}

// ---------------- Fused GRU layer: concat-K dual GEMM + gate math ----------------
// BYTE-FROZEN from R11 (passing). Concat-K over K=2048 (tiles 0..15: A=x,B=Wi;
// 16..31: A=h,B=Wh); r,z accumulate the sum; n-gate keeps i_n / h_n separate.
// Tile 128 rows x 32 gate-cols (96 reordered W rows), 4 waves (2x2).
// STAGE(t+1) ahead + one __syncthreads per tile; LDS dbuf 2x28KB, 2 blk/CU.
// L2-residency swizzle: per XCD 4 colTiles x 16 rowTiles (W set 768KB).
#define BUFSZ (224 * 64)   // (128 A-rows + 96 B-rows) * 64 k, elements
__global__ __launch_bounds__(256, 2)
void gru_fused(const unsigned short* __restrict__ x,   // [B,H] bf16 layer input
               const unsigned short* __restrict__ hb,  // [B,H] bf16 h_{t-1}
               const unsigned short* __restrict__ Wi,  // [3H,H] bf16 reordered
               const unsigned short* __restrict__ Wh,  // [3H,H] bf16 reordered
               const float* __restrict__ bih,          // [3H] original layout
               const float* __restrict__ bhh,          // [3H] original layout
               const float* __restrict__ hold,         // [B,H] fp32 h_{t-1}
               float* __restrict__ hout,               // [B,H] fp32 h'
               unsigned short* __restrict__ xout) {    // [B,H] bf16 h'
    const int bid = blockIdx.x;
    const int ii  = bid >> 3;               // 0..63 within XCD
    const int my  = ii & 15;                // row tile 0..15
    const int nxi = (bid & 7) * 4 + (ii >> 4);  // col tile 0..31

    __shared__ __align__(16) unsigned short lds[2 * BUFSZ];

    const int tid  = threadIdx.x;
    const int lane = tid & 63;
    const int w    = tid >> 6;
    const int wr   = w >> 1;         // wave row (0..1)
    const int wc   = w & 1;          // wave col / 16-col group (0..1)
    const long rowBase = (long)my * 128;
    const long colW    = (long)nxi * 96;   // reordered W row base

    f32x4 rz[4][2] = {};   // r,z gate sums (i+h), accumulated over all 32 steps
    f32x4 nin[4] = {};     // i_n (phase 0)
    f32x4 nhn[4] = {};     // h_n (phase 1)

    // Issue the 7 global_load_lds for K-tile tn into buffer buf.
    auto STAGE = [&](int tn, int buf) {
        const unsigned short* Ap = (tn < 16) ? x : hb;
        const unsigned short* Wp = (tn < 16) ? Wi : Wh;
        const long koff = (long)(tn & 15) * 64;
        unsigned short* la = lds + buf * BUFSZ;
        unsigned short* lb = la + 128 * 64;
        #pragma unroll
        for (int i = 0; i < 4; ++i) {            // A-tile: 1024 chunks
            const int cbase = (w * 4 + i) * 64;
            const int c = cbase + lane;
            const int r = c >> 3, jc = c & 7;
            const int js = (jc ^ (r & 7)) << 3;
            __builtin_amdgcn_global_load_lds(
                (gvoid_t*)(Ap + (rowBase + r) * (long)Hsz + koff + js),
                (svoid_t*)(la + cbase * 8), 16, 0, 0);
        }
        #pragma unroll
        for (int i = 0; i < 3; ++i) {            // B-tile: 768 chunks
            const int cbase = (w * 3 + i) * 64;
            const int c = cbase + lane;
            const int r = c >> 3, jc = c & 7;
            const int js = (jc ^ (r & 7)) << 3;
            __builtin_amdgcn_global_load_lds(
                (gvoid_t*)(Wp + (colW + r) * (long)Hsz + koff + js),
                (svoid_t*)(lb + cbase * 8), 16, 0, 0);
        }
    };

    auto COMPUTE = [&](int t) {
        const unsigned short* la = lds + (t & 1) * BUFSZ;
        const unsigned short* lb = la + 128 * 64;
        const bool ph0 = (t < 16);               // wave-uniform
        #pragma unroll
        for (int kk = 0; kk < 2; ++kk) {
            s16x8 av[4], bv[3];
            const int jk = kk * 4 + (lane >> 4);
            #pragma unroll
            for (int mi = 0; mi < 4; ++mi) {
                int r = wr * 64 + mi * 16 + (lane & 15);
                av[mi] = *(const s16x8*)&la[r * 64 + ((jk ^ (r & 7)) << 3)];
            }
            #pragma unroll
            for (int ni = 0; ni < 3; ++ni) {
                int r = wc * 48 + ni * 16 + (lane & 15);
                bv[ni] = *(const s16x8*)&lb[r * 64 + ((jk ^ (r & 7)) << 3)];
            }
            __builtin_amdgcn_s_setprio(1);
            #pragma unroll
            for (int mi = 0; mi < 4; ++mi) {
                mfma_bf16(rz[mi][0], av[mi], bv[0]);
                mfma_bf16(rz[mi][1], av[mi], bv[1]);
            }
            if (ph0) {
                #pragma unroll
                for (int mi = 0; mi < 4; ++mi) mfma_bf16(nin[mi], av[mi], bv[2]);
            } else {
                #pragma unroll
                for (int mi = 0; mi < 4; ++mi) mfma_bf16(nhn[mi], av[mi], bv[2]);
            }
            __builtin_amdgcn_s_setprio(0);
        }
    };

    STAGE(0, 0);
    __syncthreads();                  // vmcnt(0) drain + barrier: tile 0 ready
    #pragma unroll 2
    for (int t = 0; t < 31; ++t) {
        STAGE(t + 1, (t + 1) & 1);    // overlaps with COMPUTE(t)
        COMPUTE(t);
        __syncthreads();              // drains t+1 loads; protects buf reuse
    }
    COMPUTE(31);

    // Guard MFMA-write -> VALU-read hazard (inline-asm MFMA bypasses the
    // compiler's hazard recognizer).
    asm volatile("s_nop 7\n\ts_nop 7");

    // ---- GRU epilogue (all per-lane, no cross-lane) ----
    const int j = nxi * 32 + wc * 16 + (lane & 15);   // gate column 0..1023
    const float br = bih[j]           + bhh[j];
    const float bz = bih[Hsz + j]     + bhh[Hsz + j];
    const float bin = bih[2 * Hsz + j];
    const float bhn = bhh[2 * Hsz + j];

    #pragma unroll
    for (int mi = 0; mi < 4; ++mi) {
        #pragma unroll
        for (int q = 0; q < 4; ++q) {
            long row = rowBase + wr * 64 + mi * 16 + ((lane >> 4) << 2) + q;
            float r = sigm(rz[mi][0][q] + br);
            float z = sigm(rz[mi][1][q] + bz);
            float n = tanh_fast(nin[mi][q] + bin + r * (nhn[mi][q] + bhn));
            float hv = hold[row * Hsz + j];
            float o  = (1.0f - z) * n + z * hv;
            hout[row * Hsz + j] = o;
            xout[row * Hsz + j] = f2bf(o);
        }
    }
}

// ---------------- decoder GEMM: C = A @ W^T + b (128x128 tile, m97 structure) ----------------
__global__ __launch_bounds__(256)
void gemm_dec(const unsigned short* __restrict__ A, const unsigned short* __restrict__ Bw,
              const float* __restrict__ bias, float* __restrict__ C,
              int M, int N, int K, int nx) {
    const int nwg = gridDim.x;
    const int cpx = nwg >> 3;
    const int bid = blockIdx.x;
    const int swz = (bid & 7) * cpx + (bid >> 3);
    const int my  = swz / nx;
    const int nxi = swz - my * nx;

    __shared__ __align__(16) unsigned short lA[128 * 64];
    __shared__ __align__(16) unsigned short lB[128 * 64];

    const int tid  = threadIdx.x;
    const int lane = tid & 63;
    const int w    = tid >> 6;
    const int wr   = w >> 1;
    const int wc   = w & 1;
    const long rowBase = (long)my * 128;
    const long colBase = (long)nxi * 128;

    f32x4 acc[4][4] = {};

    for (int k0 = 0; k0 < K; k0 += 64) {
        __syncthreads();
        #pragma unroll
        for (int i = 0; i < 4; ++i) {
            const int cbase = (w * 4 + i) * 64;
            const int c = cbase + lane;
            const int r = c >> 3, jc = c & 7;
            const int js = (jc ^ (r & 7)) << 3;
            __builtin_amdgcn_global_load_lds((gvoid_t*)(A  + (rowBase + r) * (long)K + k0 + js),
                                             (svoid_t*)(lA + cbase * 8), 16, 0, 0);
            __builtin_amdgcn_global_load_lds((gvoid_t*)(Bw + (colBase + r) * (long)K + k0 + js),
                                             (svoid_t*)(lB + cbase * 8), 16, 0, 0);
        }
        __syncthreads();

        #pragma unroll
        for (int kk = 0; kk < 2; ++kk) {
            s16x8 af[4], bf[4];
            const int jk = kk * 4 + (lane >> 4);
            #pragma unroll
            for (int mi = 0; mi < 4; ++mi) {
                int r = wr * 64 + mi * 16 + (lane & 15);
                af[mi] = *(const s16x8*)&lA[r * 64 + ((jk ^ (r & 7)) << 3)];
            }
            #pragma unroll
            for (int ni = 0; ni < 4; ++ni) {
                int r = wc * 64 + ni * 16 + (lane & 15);
                bf[ni] = *(const s16x8*)&lB[r * 64 + ((jk ^ (r & 7)) << 3)];
            }
            #pragma unroll
            for (int mi = 0; mi < 4; ++mi)
                #pragma unroll
                for (int ni = 0; ni < 4; ++ni)
                    mfma_bf16(acc[mi][ni], af[mi], bf[ni]);
        }
    }

    asm volatile("s_nop 7\n\ts_nop 7");

    #pragma unroll
    for (int mi = 0; mi < 4; ++mi) {
        #pragma unroll
        for (int ni = 0; ni < 4; ++ni) {
            long col = colBase + wc * 64 + ni * 16 + (lane & 15);
            float bv = bias[col];
            #pragma unroll
            for (int q = 0; q < 4; ++q) {
                long row = rowBase + wr * 64 + mi * 16 + (lane >> 4) * 4 + q;
                C[row * (long)N + col] = acc[mi][ni][q] + bv;
            }
        }
    }
}

extern "C" void kernel_launch(void* const* d_in, const int* in_sizes, int n_in,
                              void* d_out, int out_size, void* d_ws, size_t ws_size,
                              hipStream_t stream) {
    const float* input  = (const float*)d_in[0];
    const float* hidden = (const float*)d_in[1];
    const float* i2h_w  = (const float*)d_in[2];
    const float* i2h_b  = (const float*)d_in[3];
    const float* w_ih   = (const float*)d_in[4];
    const float* w_hh   = (const float*)d_in[5];
    const float* b_ih   = (const float*)d_in[6];
    const float* b_hh   = (const float*)d_in[7];
    const float* dec_w  = (const float*)d_in[8];
    const float* dec_b  = (const float*)d_in[9];

    float* logits = (float*)d_out;                       // [B, OUT]
    float* new_h  = (float*)d_out + (size_t)Bsz * OUTsz; // [L, B, H]

    // Workspace layout (~76 MB)
    char* p = (char*)d_ws;
    unsigned short* wih16  = (unsigned short*)p; p += (size_t)Lsz * 3 * Hsz * Hsz * 2;
    unsigned short* whh16  = (unsigned short*)p; p += (size_t)Lsz * 3 * Hsz * Hsz * 2;
    unsigned short* wdec16 = (unsigned short*)p; p += (size_t)OUTsz * Hsz * 2;
    unsigned short* h16    = (unsigned short*)p; p += (size_t)Lsz * Bsz * Hsz * 2;
    unsigned short* xb0    = (unsigned short*)p; p += (size_t)Bsz * Hsz * 2;
    unsigned short* xb1    = (unsigned short*)p; p += (size_t)Bsz * Hsz * 2;
    unsigned short* xbuf[2] = { xb0, xb1 };

    // 1) ALL pre-work in one launch: weight reorders + dec cast + hidden cast + i2h
    prework<<<24704, 256, 0, stream>>>(w_ih, wih16, w_hh, whh16,
                                       dec_w, wdec16, hidden, h16,
                                       input, i2h_w, i2h_b, xb0);

    // 2) fused GRU layers (one launch each; BYTE-FROZEN kernel)
    for (int l = 0; l < Lsz; ++l) {
        gru_fused<<<512, 256, 0, stream>>>(
            xbuf[l & 1],
            h16 + (size_t)l * Bsz * Hsz,
            wih16 + (size_t)l * 3 * Hsz * Hsz,
            whh16 + (size_t)l * 3 * Hsz * Hsz,
            b_ih + (size_t)l * 3 * Hsz,
            b_hh + (size_t)l * 3 * Hsz,
            hidden + (size_t)l * Bsz * Hsz,
            new_h + (size_t)l * Bsz * Hsz,
            xbuf[(l + 1) & 1]);
    }

    // 3) decoder: logits = h3 @ dec_w.T + dec_b   (h3 is in xbuf[0] after 4 layers)
    {
        int nx = OUTsz / 128;                          // 2
        int blocks = nx * (Bsz / 128);                 // 32
        gemm_dec<<<blocks, 256, 0, stream>>>(xbuf[Lsz & 1], wdec16, dec_b, logits,
                                             Bsz, OUTsz, Hsz, nx);
    }
}

// Round 13
// 167.850 us; speedup vs baseline: 4.4386x; 1.0017x over previous
//
#include <hip/hip_runtime.h>
#include <cstdint>
#include <cstddef>

// Problem constants (from reference): B=2048, IN=4, H=1024, L=4, OUT=256
#define Bsz   2048
#define INsz  4
#define Hsz   1024
#define Lsz   4
#define OUTsz 256

// ============================================================================
// ANCHOR: R12 passed (168.1 µs, absmax 2.93e-3). gru_fused and gemm_dec are
// BYTE-FROZEN (5 structural gru redesigns -> 5 deterministic numerical
// failures, R5-R8+R10). This round touches ONLY prework: R12 profiling showed
// 59.9 µs @ 2.33 TB/s with 24,704 single-op blocks (block-launch-overhead
// bound, G11). Now: 4096 blocks, grid-stride over a unified work-item space,
// bodies verbatim (bit-identical outputs); i2h vectorized 4-wide (same
// per-element fp32 arithmetic order).
// ============================================================================

typedef float f32x4 __attribute__((ext_vector_type(4)));
typedef short s16x8 __attribute__((ext_vector_type(8)));

typedef __attribute__((address_space(1))) void gvoid_t;  // global
typedef __attribute__((address_space(3))) void svoid_t;  // LDS

__device__ __forceinline__ unsigned short f2bf(float f) {
    union { float f; unsigned int u; } v; v.f = f;
    unsigned int r = 0x7FFFu + ((v.u >> 16) & 1u);
    return (unsigned short)((v.u + r) >> 16);
}

__device__ __forceinline__ float sigm(float x) {
    return 1.0f / (1.0f + __expf(-x));
}
__device__ __forceinline__ float tanh_fast(float x) {
    float a = __expf(-2.0f * fabsf(x));
    float t = (1.0f - a) / (1.0f + a);
    return copysignf(t, x);
}

// Inline-asm MFMA: signature-proof vs builtin bf16/short ambiguity.
__device__ __forceinline__ void mfma_bf16(f32x4& c, s16x8 a, s16x8 b) {
    asm("v_mfma_f32_16x16x32_bf16 %0, %1, %2, %0" : "+v"(c) : "v"(a), "v"(b));
}

// ---------------- pre-work bodies (arithmetic identical to proven kernels) ----------------
__device__ __forceinline__ void body_cast8(const float* __restrict__ in,
                                           unsigned short* __restrict__ out, int i) {
    const float4* p = (const float4*)in;
    float4 a = p[2 * i], b = p[2 * i + 1];
    union { unsigned short s[8]; uint4 u; } o;
    o.s[0] = f2bf(a.x); o.s[1] = f2bf(a.y); o.s[2] = f2bf(a.z); o.s[3] = f2bf(a.w);
    o.s[4] = f2bf(b.x); o.s[5] = f2bf(b.y); o.s[6] = f2bf(b.z); o.s[7] = f2bf(b.w);
    ((uint4*)out)[i] = o.u;
}

// weight gate-group reorder: out row' = l*3H + (j>>4)*48 + gate*16 + (j&15)
__device__ __forceinline__ void body_reorder(const float* __restrict__ in,
                                             unsigned short* __restrict__ out, int i) {
    int k8  = i & (Hsz / 8 - 1);          // 128 chunks per row
    int row = i >> 7;
    int l    = row / (3 * Hsz);
    int lrow = row - l * (3 * Hsz);
    int gate = lrow >> 10;
    int j    = lrow & (Hsz - 1);
    int rowp = l * (3 * Hsz) + ((j >> 4) * 48) + gate * 16 + (j & 15);
    const float4* p = (const float4*)(in + (size_t)row * Hsz + k8 * 8);
    float4 a = p[0], b = p[1];
    union { unsigned short s[8]; uint4 u; } o;
    o.s[0] = f2bf(a.x); o.s[1] = f2bf(a.y); o.s[2] = f2bf(a.z); o.s[3] = f2bf(a.w);
    o.s[4] = f2bf(b.x); o.s[5] = f2bf(b.y); o.s[6] = f2bf(b.z); o.s[7] = f2bf(b.w);
    *(uint4*)(out + (size_t)rowp * Hsz + k8 * 8) = o.u;
}

// i2h, 4 columns per item: same per-element fp32 arithmetic as the proven
// scalar body (dot(xi,wj) + b[j]), vectorized store (ushort4).
__device__ __forceinline__ void body_i2h4(const float* __restrict__ inp,
                                          const float* __restrict__ w,
                                          const float* __restrict__ b,
                                          unsigned short* __restrict__ xb, int idx) {
    int m  = idx >> 8;               // batch row (256 items of 4 cols per row)
    int j0 = (idx & 255) << 2;       // first of 4 columns
    float4 xi = ((const float4*)inp)[m];
    float4 bv = *(const float4*)(b + j0);
    ushort4 o;
    {
        float4 wj = ((const float4*)w)[j0 + 0];
        o.x = f2bf(xi.x * wj.x + xi.y * wj.y + xi.z * wj.z + xi.w * wj.w + bv.x);
    }
    {
        float4 wj = ((const float4*)w)[j0 + 1];
        o.y = f2bf(xi.x * wj.x + xi.y * wj.y + xi.z * wj.z + xi.w * wj.w + bv.y);
    }
    {
        float4 wj = ((const float4*)w)[j0 + 2];
        o.z = f2bf(xi.x * wj.x + xi.y * wj.y + xi.z * wj.z + xi.w * wj.w + bv.z);
    }
    {
        float4 wj = ((const float4*)w)[j0 + 3];
        o.w = f2bf(xi.x * wj.x + xi.y * wj.y + xi.z * wj.z + xi.w * wj.w + bv.w);
    }
    *(ushort4*)(xb + (size_t)m * Hsz + j0) = o;
}

// ---------------- ONE grid-stride pre-work launch (G11 form) ----------------
// Unified work-item space (all counts exact):
//   [0, 1572864)          w_ih reorder (8-elem chunks)
//   [1572864, 3145728)    w_hh reorder
//   [3145728, 3178496)    dec_w cast
//   [3178496, 4227072)    hidden cast
//   [4227072, 4751360)    i2h (4-col items)
#define PW_N1 1572864
#define PW_N2 3145728
#define PW_N3 3178496
#define PW_N4 4227072
#define PW_TOT 4751360
__global__ void prework(const float* __restrict__ w_ih, unsigned short* __restrict__ wih16,
                        const float* __restrict__ w_hh, unsigned short* __restrict__ whh16,
                        const float* __restrict__ dec_w, unsigned short* __restrict__ wdec16,
                        const float* __restrict__ hidden, unsigned short* __restrict__ h16,
                        const float* __restrict__ input, const float* __restrict__ i2h_w,
                        const float* __restrict__ i2h_b, unsigned short* __restrict__ xb0) {
    const int stride = gridDim.x * blockDim.x;
    for (int t = blockIdx.x * blockDim.x + threadIdx.x; t < PW_TOT; t += stride) {
        if (t < PW_N1)      body_reorder(w_ih, wih16, t);
        else if (t < PW_N2) body_reorder(w_hh, whh16, t - PW_N1);
        else if (t < PW_N3) body_cast8(dec_w, wdec16, t - PW_N2);
        else if (t < PW_N4) body_cast8(hidden, h16, t - PW_N3);
        else                body_i2h4(input, i2h_w, i2h_b, xb0, t - PW_N4);
    }
}

// ---------------- Fused GRU layer: concat-K dual GEMM + gate math ----------------
// BYTE-FROZEN from R11/R12 (passing). Concat-K over K=2048 (tiles 0..15:
// A=x,B=Wi; 16..31: A=h,B=Wh); r,z accumulate the sum; n-gate keeps i_n / h_n
// separate. Tile 128 rows x 32 gate-cols (96 reordered W rows), 4 waves (2x2).
// STAGE(t+1) ahead + one __syncthreads per tile; LDS dbuf 2x28KB, 2 blk/CU.
// L2-residency swizzle: per XCD 4 colTiles x 16 rowTiles (W set 768KB).
#define BUFSZ (224 * 64)   // (128 A-rows + 96 B-rows) * 64 k, elements
__global__ __launch_bounds__(256, 2)
void gru_fused(const unsigned short* __restrict__ x,   // [B,H] bf16 layer input
               const unsigned short* __restrict__ hb,  // [B,H] bf16 h_{t-1}
               const unsigned short* __restrict__ Wi,  // [3H,H] bf16 reordered
               const unsigned short* __restrict__ Wh,  // [3H,H] bf16 reordered
               const float* __restrict__ bih,          // [3H] original layout
               const float* __restrict__ bhh,          // [3H] original layout
               const float* __restrict__ hold,         // [B,H] fp32 h_{t-1}
               float* __restrict__ hout,               // [B,H] fp32 h'
               unsigned short* __restrict__ xout) {    // [B,H] bf16 h'
    const int bid = blockIdx.x;
    const int ii  = bid >> 3;               // 0..63 within XCD
    const int my  = ii & 15;                // row tile 0..15
    const int nxi = (bid & 7) * 4 + (ii >> 4);  // col tile 0..31

    __shared__ __align__(16) unsigned short lds[2 * BUFSZ];

    const int tid  = threadIdx.x;
    const int lane = tid & 63;
    const int w    = tid >> 6;
    const int wr   = w >> 1;         // wave row (0..1)
    const int wc   = w & 1;          // wave col / 16-col group (0..1)
    const long rowBase = (long)my * 128;
    const long colW    = (long)nxi * 96;   // reordered W row base

    f32x4 rz[4][2] = {};   // r,z gate sums (i+h), accumulated over all 32 steps
    f32x4 nin[4] = {};     // i_n (phase 0)
    f32x4 nhn[4] = {};     // h_n (phase 1)

    // Issue the 7 global_load_lds for K-tile tn into buffer buf.
    auto STAGE = [&](int tn, int buf) {
        const unsigned short* Ap = (tn < 16) ? x : hb;
        const unsigned short* Wp = (tn < 16) ? Wi : Wh;
        const long koff = (long)(tn & 15) * 64;
        unsigned short* la = lds + buf * BUFSZ;
        unsigned short* lb = la + 128 * 64;
        #pragma unroll
        for (int i = 0; i < 4; ++i) {            // A-tile: 1024 chunks
            const int cbase = (w * 4 + i) * 64;
            const int c = cbase + lane;
            const int r = c >> 3, jc = c & 7;
            const int js = (jc ^ (r & 7)) << 3;
            __builtin_amdgcn_global_load_lds(
                (gvoid_t*)(Ap + (rowBase + r) * (long)Hsz + koff + js),
                (svoid_t*)(la + cbase * 8), 16, 0, 0);
        }
        #pragma unroll
        for (int i = 0; i < 3; ++i) {            // B-tile: 768 chunks
            const int cbase = (w * 3 + i) * 64;
            const int c = cbase + lane;
            const int r = c >> 3, jc = c & 7;
            const int js = (jc ^ (r & 7)) << 3;
            __builtin_amdgcn_global_load_lds(
                (gvoid_t*)(Wp + (colW + r) * (long)Hsz + koff + js),
                (svoid_t*)(lb + cbase * 8), 16, 0, 0);
        }
    };

    auto COMPUTE = [&](int t) {
        const unsigned short* la = lds + (t & 1) * BUFSZ;
        const unsigned short* lb = la + 128 * 64;
        const bool ph0 = (t < 16);               // wave-uniform
        #pragma unroll
        for (int kk = 0; kk < 2; ++kk) {
            s16x8 av[4], bv[3];
            const int jk = kk * 4 + (lane >> 4);
            #pragma unroll
            for (int mi = 0; mi < 4; ++mi) {
                int r = wr * 64 + mi * 16 + (lane & 15);
                av[mi] = *(const s16x8*)&la[r * 64 + ((jk ^ (r & 7)) << 3)];
            }
            #pragma unroll
            for (int ni = 0; ni < 3; ++ni) {
                int r = wc * 48 + ni * 16 + (lane & 15);
                bv[ni] = *(const s16x8*)&lb[r * 64 + ((jk ^ (r & 7)) << 3)];
            }
            __builtin_amdgcn_s_setprio(1);
            #pragma unroll
            for (int mi = 0; mi < 4; ++mi) {
                mfma_bf16(rz[mi][0], av[mi], bv[0]);
                mfma_bf16(rz[mi][1], av[mi], bv[1]);
            }
            if (ph0) {
                #pragma unroll
                for (int mi = 0; mi < 4; ++mi) mfma_bf16(nin[mi], av[mi], bv[2]);
            } else {
                #pragma unroll
                for (int mi = 0; mi < 4; ++mi) mfma_bf16(nhn[mi], av[mi], bv[2]);
            }
            __builtin_amdgcn_s_setprio(0);
        }
    };

    STAGE(0, 0);
    __syncthreads();                  // vmcnt(0) drain + barrier: tile 0 ready
    #pragma unroll 2
    for (int t = 0; t < 31; ++t) {
        STAGE(t + 1, (t + 1) & 1);    // overlaps with COMPUTE(t)
        COMPUTE(t);
        __syncthreads();              // drains t+1 loads; protects buf reuse
    }
    COMPUTE(31);

    // Guard MFMA-write -> VALU-read hazard (inline-asm MFMA bypasses the
    // compiler's hazard recognizer).
    asm volatile("s_nop 7\n\ts_nop 7");

    // ---- GRU epilogue (all per-lane, no cross-lane) ----
    const int j = nxi * 32 + wc * 16 + (lane & 15);   // gate column 0..1023
    const float br = bih[j]           + bhh[j];
    const float bz = bih[Hsz + j]     + bhh[Hsz + j];
    const float bin = bih[2 * Hsz + j];
    const float bhn = bhh[2 * Hsz + j];

    #pragma unroll
    for (int mi = 0; mi < 4; ++mi) {
        #pragma unroll
        for (int q = 0; q < 4; ++q) {
            long row = rowBase + wr * 64 + mi * 16 + ((lane >> 4) << 2) + q;
            float r = sigm(rz[mi][0][q] + br);
            float z = sigm(rz[mi][1][q] + bz);
            float n = tanh_fast(nin[mi][q] + bin + r * (nhn[mi][q] + bhn));
            float hv = hold[row * Hsz + j];
            float o  = (1.0f - z) * n + z * hv;
            hout[row * Hsz + j] = o;
            xout[row * Hsz + j] = f2bf(o);
        }
    }
}

// ---------------- decoder GEMM: C = A @ W^T + b (128x128 tile, m97 structure) ----------------
__global__ __launch_bounds__(256)
void gemm_dec(const unsigned short* __restrict__ A, const unsigned short* __restrict__ Bw,
              const float* __restrict__ bias, float* __restrict__ C,
              int M, int N, int K, int nx) {
    const int nwg = gridDim.x;
    const int cpx = nwg >> 3;
    const int bid = blockIdx.x;
    const int swz = (bid & 7) * cpx + (bid >> 3);
    const int my  = swz / nx;
    const int nxi = swz - my * nx;

    __shared__ __align__(16) unsigned short lA[128 * 64];
    __shared__ __align__(16) unsigned short lB[128 * 64];

    const int tid  = threadIdx.x;
    const int lane = tid & 63;
    const int w    = tid >> 6;
    const int wr   = w >> 1;
    const int wc   = w & 1;
    const long rowBase = (long)my * 128;
    const long colBase = (long)nxi * 128;

    f32x4 acc[4][4] = {};

    for (int k0 = 0; k0 < K; k0 += 64) {
        __syncthreads();
        #pragma unroll
        for (int i = 0; i < 4; ++i) {
            const int cbase = (w * 4 + i) * 64;
            const int c = cbase + lane;
            const int r = c >> 3, jc = c & 7;
            const int js = (jc ^ (r & 7)) << 3;
            __builtin_amdgcn_global_load_lds((gvoid_t*)(A  + (rowBase + r) * (long)K + k0 + js),
                                             (svoid_t*)(lA + cbase * 8), 16, 0, 0);
            __builtin_amdgcn_global_load_lds((gvoid_t*)(Bw + (colBase + r) * (long)K + k0 + js),
                                             (svoid_t*)(lB + cbase * 8), 16, 0, 0);
        }
        __syncthreads();

        #pragma unroll
        for (int kk = 0; kk < 2; ++kk) {
            s16x8 af[4], bf[4];
            const int jk = kk * 4 + (lane >> 4);
            #pragma unroll
            for (int mi = 0; mi < 4; ++mi) {
                int r = wr * 64 + mi * 16 + (lane & 15);
                af[mi] = *(const s16x8*)&lA[r * 64 + ((jk ^ (r & 7)) << 3)];
            }
            #pragma unroll
            for (int ni = 0; ni < 4; ++ni) {
                int r = wc * 64 + ni * 16 + (lane & 15);
                bf[ni] = *(const s16x8*)&lB[r * 64 + ((jk ^ (r & 7)) << 3)];
            }
            #pragma unroll
            for (int mi = 0; mi < 4; ++mi)
                #pragma unroll
                for (int ni = 0; ni < 4; ++ni)
                    mfma_bf16(acc[mi][ni], af[mi], bf[ni]);
        }
    }

    asm volatile("s_nop 7\n\ts_nop 7");

    #pragma unroll
    for (int mi = 0; mi < 4; ++mi) {
        #pragma unroll
        for (int ni = 0; ni < 4; ++ni) {
            long col = colBase + wc * 64 + ni * 16 + (lane & 15);
            float bv = bias[col];
            #pragma unroll
            for (int q = 0; q < 4; ++q) {
                long row = rowBase + wr * 64 + mi * 16 + (lane >> 4) * 4 + q;
                C[row * (long)N + col] = acc[mi][ni][q] + bv;
            }
        }
    }
}

extern "C" void kernel_launch(void* const* d_in, const int* in_sizes, int n_in,
                              void* d_out, int out_size, void* d_ws, size_t ws_size,
                              hipStream_t stream) {
    const float* input  = (const float*)d_in[0];
    const float* hidden = (const float*)d_in[1];
    const float* i2h_w  = (const float*)d_in[2];
    const float* i2h_b  = (const float*)d_in[3];
    const float* w_ih   = (const float*)d_in[4];
    const float* w_hh   = (const float*)d_in[5];
    const float* b_ih   = (const float*)d_in[6];
    const float* b_hh   = (const float*)d_in[7];
    const float* dec_w  = (const float*)d_in[8];
    const float* dec_b  = (const float*)d_in[9];

    float* logits = (float*)d_out;                       // [B, OUT]
    float* new_h  = (float*)d_out + (size_t)Bsz * OUTsz; // [L, B, H]

    // Workspace layout (~76 MB)
    char* p = (char*)d_ws;
    unsigned short* wih16  = (unsigned short*)p; p += (size_t)Lsz * 3 * Hsz * Hsz * 2;
    unsigned short* whh16  = (unsigned short*)p; p += (size_t)Lsz * 3 * Hsz * Hsz * 2;
    unsigned short* wdec16 = (unsigned short*)p; p += (size_t)OUTsz * Hsz * 2;
    unsigned short* h16    = (unsigned short*)p; p += (size_t)Lsz * Bsz * Hsz * 2;
    unsigned short* xb0    = (unsigned short*)p; p += (size_t)Bsz * Hsz * 2;
    unsigned short* xb1    = (unsigned short*)p; p += (size_t)Bsz * Hsz * 2;
    unsigned short* xbuf[2] = { xb0, xb1 };

    // 1) ALL pre-work in one grid-stride launch (G11: 4096 blocks, ~4.5 items/thread)
    prework<<<4096, 256, 0, stream>>>(w_ih, wih16, w_hh, whh16,
                                      dec_w, wdec16, hidden, h16,
                                      input, i2h_w, i2h_b, xb0);

    // 2) fused GRU layers (one launch each; BYTE-FROZEN kernel)
    for (int l = 0; l < Lsz; ++l) {
        gru_fused<<<512, 256, 0, stream>>>(
            xbuf[l & 1],
            h16 + (size_t)l * Bsz * Hsz,
            wih16 + (size_t)l * 3 * Hsz * Hsz,
            whh16 + (size_t)l * 3 * Hsz * Hsz,
            b_ih + (size_t)l * 3 * Hsz,
            b_hh + (size_t)l * 3 * Hsz,
            hidden + (size_t)l * Bsz * Hsz,
            new_h + (size_t)l * Bsz * Hsz,
            xbuf[(l + 1) & 1]);
    }

    // 3) decoder: logits = h3 @ dec_w.T + dec_b   (h3 is in xbuf[0] after 4 layers)
    {
        int nx = OUTsz / 128;                          // 2
        int blocks = nx * (Bsz / 128);                 // 32
        gemm_dec<<<blocks, 256, 0, stream>>>(xbuf[Lsz & 1], wdec16, dec_b, logits,
                                             Bsz, OUTsz, Hsz, nx);
    }
}

// Round 14
// 167.463 us; speedup vs baseline: 4.4489x; 1.0023x over previous
//
#include <hip/hip_runtime.h>
#include <cstdint>
#include <cstddef>

// Problem constants (from reference): B=2048, IN=4, H=1024, L=4, OUT=256
#define Bsz   2048
#define INsz  4
#define Hsz   1024
#define Lsz   4
#define OUTsz 256

// ============================================================================
// ANCHOR: R13 passed (167.9 µs, absmax 2.93e-3). gru_fused sync skeleton,
// fragment scheme, tile geometry and ALL address VALUES are FROZEN (5
// structural redesigns -> 5 deterministic numerical failures, R5-R8+R10).
// R14 change (arithmetic-identical): hoist loop-invariant STAGE address
// offsets out of the K-loop (same address values, computed once) and fully
// unroll the t-loop. No change to sync, math, or memory access patterns.
// ============================================================================

typedef float f32x4 __attribute__((ext_vector_type(4)));
typedef short s16x8 __attribute__((ext_vector_type(8)));

typedef __attribute__((address_space(1))) void gvoid_t;  // global
typedef __attribute__((address_space(3))) void svoid_t;  // LDS

__device__ __forceinline__ unsigned short f2bf(float f) {
    union { float f; unsigned int u; } v; v.f = f;
    unsigned int r = 0x7FFFu + ((v.u >> 16) & 1u);
    return (unsigned short)((v.u + r) >> 16);
}

__device__ __forceinline__ float sigm(float x) {
    return 1.0f / (1.0f + __expf(-x));
}
__device__ __forceinline__ float tanh_fast(float x) {
    float a = __expf(-2.0f * fabsf(x));
    float t = (1.0f - a) / (1.0f + a);
    return copysignf(t, x);
}

// Inline-asm MFMA: signature-proof vs builtin bf16/short ambiguity.
__device__ __forceinline__ void mfma_bf16(f32x4& c, s16x8 a, s16x8 b) {
    asm("v_mfma_f32_16x16x32_bf16 %0, %1, %2, %0" : "+v"(c) : "v"(a), "v"(b));
}

// ---------------- pre-work bodies (arithmetic identical to proven kernels) ----------------
__device__ __forceinline__ void body_cast8(const float* __restrict__ in,
                                           unsigned short* __restrict__ out, int i) {
    const float4* p = (const float4*)in;
    float4 a = p[2 * i], b = p[2 * i + 1];
    union { unsigned short s[8]; uint4 u; } o;
    o.s[0] = f2bf(a.x); o.s[1] = f2bf(a.y); o.s[2] = f2bf(a.z); o.s[3] = f2bf(a.w);
    o.s[4] = f2bf(b.x); o.s[5] = f2bf(b.y); o.s[6] = f2bf(b.z); o.s[7] = f2bf(b.w);
    ((uint4*)out)[i] = o.u;
}

// weight gate-group reorder: out row' = l*3H + (j>>4)*48 + gate*16 + (j&15)
__device__ __forceinline__ void body_reorder(const float* __restrict__ in,
                                             unsigned short* __restrict__ out, int i) {
    int k8  = i & (Hsz / 8 - 1);          // 128 chunks per row
    int row = i >> 7;
    int l    = row / (3 * Hsz);
    int lrow = row - l * (3 * Hsz);
    int gate = lrow >> 10;
    int j    = lrow & (Hsz - 1);
    int rowp = l * (3 * Hsz) + ((j >> 4) * 48) + gate * 16 + (j & 15);
    const float4* p = (const float4*)(in + (size_t)row * Hsz + k8 * 8);
    float4 a = p[0], b = p[1];
    union { unsigned short s[8]; uint4 u; } o;
    o.s[0] = f2bf(a.x); o.s[1] = f2bf(a.y); o.s[2] = f2bf(a.z); o.s[3] = f2bf(a.w);
    o.s[4] = f2bf(b.x); o.s[5] = f2bf(b.y); o.s[6] = f2bf(b.z); o.s[7] = f2bf(b.w);
    *(uint4*)(out + (size_t)rowp * Hsz + k8 * 8) = o.u;
}

// i2h, 4 columns per item: same per-element fp32 arithmetic as the proven
// scalar body (dot(xi,wj) + b[j]), vectorized store (ushort4).
__device__ __forceinline__ void body_i2h4(const float* __restrict__ inp,
                                          const float* __restrict__ w,
                                          const float* __restrict__ b,
                                          unsigned short* __restrict__ xb, int idx) {
    int m  = idx >> 8;               // batch row (256 items of 4 cols per row)
    int j0 = (idx & 255) << 2;       // first of 4 columns
    float4 xi = ((const float4*)inp)[m];
    float4 bv = *(const float4*)(b + j0);
    ushort4 o;
    {
        float4 wj = ((const float4*)w)[j0 + 0];
        o.x = f2bf(xi.x * wj.x + xi.y * wj.y + xi.z * wj.z + xi.w * wj.w + bv.x);
    }
    {
        float4 wj = ((const float4*)w)[j0 + 1];
        o.y = f2bf(xi.x * wj.x + xi.y * wj.y + xi.z * wj.z + xi.w * wj.w + bv.y);
    }
    {
        float4 wj = ((const float4*)w)[j0 + 2];
        o.z = f2bf(xi.x * wj.x + xi.y * wj.y + xi.z * wj.z + xi.w * wj.w + bv.z);
    }
    {
        float4 wj = ((const float4*)w)[j0 + 3];
        o.w = f2bf(xi.x * wj.x + xi.y * wj.y + xi.z * wj.z + xi.w * wj.w + bv.w);
    }
    *(ushort4*)(xb + (size_t)m * Hsz + j0) = o;
}

// ---------------- ONE grid-stride pre-work launch (G11 form) ----------------
#define PW_N1 1572864
#define PW_N2 3145728
#define PW_N3 3178496
#define PW_N4 4227072
#define PW_TOT 4751360
__global__ void prework(const float* __restrict__ w_ih, unsigned short* __restrict__ wih16,
                        const float* __restrict__ w_hh, unsigned short* __restrict__ whh16,
                        const float* __restrict__ dec_w, unsigned short* __restrict__ wdec16,
                        const float* __restrict__ hidden, unsigned short* __restrict__ h16,
                        const float* __restrict__ input, const float* __restrict__ i2h_w,
                        const float* __restrict__ i2h_b, unsigned short* __restrict__ xb0) {
    const int stride = gridDim.x * blockDim.x;
    for (int t = blockIdx.x * blockDim.x + threadIdx.x; t < PW_TOT; t += stride) {
        if (t < PW_N1)      body_reorder(w_ih, wih16, t);
        else if (t < PW_N2) body_reorder(w_hh, whh16, t - PW_N1);
        else if (t < PW_N3) body_cast8(dec_w, wdec16, t - PW_N2);
        else if (t < PW_N4) body_cast8(hidden, h16, t - PW_N3);
        else                body_i2h4(input, i2h_w, i2h_b, xb0, t - PW_N4);
    }
}

// ---------------- Fused GRU layer: concat-K dual GEMM + gate math ----------------
// FROZEN structure from R11/R13 (passing). Concat-K over K=2048 (tiles 0..15:
// A=x,B=Wi; 16..31: A=h,B=Wh); r,z accumulate the sum; n-gate keeps i_n / h_n
// separate. Tile 128 rows x 32 gate-cols (96 reordered W rows), 4 waves (2x2).
// STAGE(t+1) ahead + one __syncthreads per tile; LDS dbuf 2x28KB, 2 blk/CU.
// L2-residency swizzle: per XCD 4 colTiles x 16 rowTiles (W set 768KB).
// R14: loop-invariant STAGE offsets hoisted (identical address values),
// t-loop fully unrolled. Sync/math/access pattern unchanged.
#define BUFSZ (224 * 64)   // (128 A-rows + 96 B-rows) * 64 k, elements
__global__ __launch_bounds__(256, 2)
void gru_fused(const unsigned short* __restrict__ x,   // [B,H] bf16 layer input
               const unsigned short* __restrict__ hb,  // [B,H] bf16 h_{t-1}
               const unsigned short* __restrict__ Wi,  // [3H,H] bf16 reordered
               const unsigned short* __restrict__ Wh,  // [3H,H] bf16 reordered
               const float* __restrict__ bih,          // [3H] original layout
               const float* __restrict__ bhh,          // [3H] original layout
               const float* __restrict__ hold,         // [B,H] fp32 h_{t-1}
               float* __restrict__ hout,               // [B,H] fp32 h'
               unsigned short* __restrict__ xout) {    // [B,H] bf16 h'
    const int bid = blockIdx.x;
    const int ii  = bid >> 3;               // 0..63 within XCD
    const int my  = ii & 15;                // row tile 0..15
    const int nxi = (bid & 7) * 4 + (ii >> 4);  // col tile 0..31

    __shared__ __align__(16) unsigned short lds[2 * BUFSZ];

    const int tid  = threadIdx.x;
    const int lane = tid & 63;
    const int w    = tid >> 6;
    const int wr   = w >> 1;         // wave row (0..1)
    const int wc   = w & 1;          // wave col / 16-col group (0..1)
    const long rowBase = (long)my * 128;
    const long colW    = (long)nxi * 96;   // reordered W row base

    f32x4 rz[4][2] = {};   // r,z gate sums (i+h), accumulated over all 32 steps
    f32x4 nin[4] = {};     // i_n (phase 0)
    f32x4 nhn[4] = {};     // h_n (phase 1)

    // ---- hoisted loop-invariant STAGE geometry (identical address values) ----
    long aoffE[4];                   // A-tile: global element offset per chunk i
    int  acb[4];                     // A-tile: LDS chunk base per i
    #pragma unroll
    for (int i = 0; i < 4; ++i) {
        const int cbase = (w * 4 + i) * 64;
        const int c = cbase + lane;
        const int r = c >> 3, jc = c & 7;
        const int js = (jc ^ (r & 7)) << 3;
        aoffE[i] = (rowBase + r) * (long)Hsz + js;
        acb[i]   = cbase;
    }
    long boffE[3];                   // B-tile
    int  bcb[3];
    #pragma unroll
    for (int i = 0; i < 3; ++i) {
        const int cbase = (w * 3 + i) * 64;
        const int c = cbase + lane;
        const int r = c >> 3, jc = c & 7;
        const int js = (jc ^ (r & 7)) << 3;
        boffE[i] = (colW + r) * (long)Hsz + js;
        bcb[i]   = cbase;
    }

    // Issue the 7 global_load_lds for K-tile tn into buffer buf.
    auto STAGE = [&](int tn, int buf) {
        const unsigned short* Ap = (tn < 16) ? x : hb;
        const unsigned short* Wp = (tn < 16) ? Wi : Wh;
        const long koff = (long)(tn & 15) * 64;
        unsigned short* la = lds + buf * BUFSZ;
        unsigned short* lb = la + 128 * 64;
        #pragma unroll
        for (int i = 0; i < 4; ++i)
            __builtin_amdgcn_global_load_lds((gvoid_t*)(Ap + aoffE[i] + koff),
                                             (svoid_t*)(la + acb[i] * 8), 16, 0, 0);
        #pragma unroll
        for (int i = 0; i < 3; ++i)
            __builtin_amdgcn_global_load_lds((gvoid_t*)(Wp + boffE[i] + koff),
                                             (svoid_t*)(lb + bcb[i] * 8), 16, 0, 0);
    };

    auto COMPUTE = [&](int t) {
        const unsigned short* la = lds + (t & 1) * BUFSZ;
        const unsigned short* lb = la + 128 * 64;
        const bool ph0 = (t < 16);               // wave-uniform
        #pragma unroll
        for (int kk = 0; kk < 2; ++kk) {
            s16x8 av[4], bv[3];
            const int jk = kk * 4 + (lane >> 4);
            #pragma unroll
            for (int mi = 0; mi < 4; ++mi) {
                int r = wr * 64 + mi * 16 + (lane & 15);
                av[mi] = *(const s16x8*)&la[r * 64 + ((jk ^ (r & 7)) << 3)];
            }
            #pragma unroll
            for (int ni = 0; ni < 3; ++ni) {
                int r = wc * 48 + ni * 16 + (lane & 15);
                bv[ni] = *(const s16x8*)&lb[r * 64 + ((jk ^ (r & 7)) << 3)];
            }
            __builtin_amdgcn_s_setprio(1);
            #pragma unroll
            for (int mi = 0; mi < 4; ++mi) {
                mfma_bf16(rz[mi][0], av[mi], bv[0]);
                mfma_bf16(rz[mi][1], av[mi], bv[1]);
            }
            if (ph0) {
                #pragma unroll
                for (int mi = 0; mi < 4; ++mi) mfma_bf16(nin[mi], av[mi], bv[2]);
            } else {
                #pragma unroll
                for (int mi = 0; mi < 4; ++mi) mfma_bf16(nhn[mi], av[mi], bv[2]);
            }
            __builtin_amdgcn_s_setprio(0);
        }
    };

    STAGE(0, 0);
    __syncthreads();                  // vmcnt(0) drain + barrier: tile 0 ready
    #pragma unroll
    for (int t = 0; t < 31; ++t) {
        STAGE(t + 1, (t + 1) & 1);    // overlaps with COMPUTE(t)
        COMPUTE(t);
        __syncthreads();              // drains t+1 loads; protects buf reuse
    }
    COMPUTE(31);

    // Guard MFMA-write -> VALU-read hazard (inline-asm MFMA bypasses the
    // compiler's hazard recognizer).
    asm volatile("s_nop 7\n\ts_nop 7");

    // ---- GRU epilogue (all per-lane, no cross-lane) ----
    const int j = nxi * 32 + wc * 16 + (lane & 15);   // gate column 0..1023
    const float br = bih[j]           + bhh[j];
    const float bz = bih[Hsz + j]     + bhh[Hsz + j];
    const float bin = bih[2 * Hsz + j];
    const float bhn = bhh[2 * Hsz + j];

    #pragma unroll
    for (int mi = 0; mi < 4; ++mi) {
        #pragma unroll
        for (int q = 0; q < 4; ++q) {
            long row = rowBase + wr * 64 + mi * 16 + ((lane >> 4) << 2) + q;
            float r = sigm(rz[mi][0][q] + br);
            float z = sigm(rz[mi][1][q] + bz);
            float n = tanh_fast(nin[mi][q] + bin + r * (nhn[mi][q] + bhn));
            float hv = hold[row * Hsz + j];
            float o  = (1.0f - z) * n + z * hv;
            hout[row * Hsz + j] = o;
            xout[row * Hsz + j] = f2bf(o);
        }
    }
}

// ---------------- decoder GEMM: C = A @ W^T + b (128x128 tile, m97 structure) ----------------
__global__ __launch_bounds__(256)
void gemm_dec(const unsigned short* __restrict__ A, const unsigned short* __restrict__ Bw,
              const float* __restrict__ bias, float* __restrict__ C,
              int M, int N, int K, int nx) {
    const int nwg = gridDim.x;
    const int cpx = nwg >> 3;
    const int bid = blockIdx.x;
    const int swz = (bid & 7) * cpx + (bid >> 3);
    const int my  = swz / nx;
    const int nxi = swz - my * nx;

    __shared__ __align__(16) unsigned short lA[128 * 64];
    __shared__ __align__(16) unsigned short lB[128 * 64];

    const int tid  = threadIdx.x;
    const int lane = tid & 63;
    const int w    = tid >> 6;
    const int wr   = w >> 1;
    const int wc   = w & 1;
    const long rowBase = (long)my * 128;
    const long colBase = (long)nxi * 128;

    f32x4 acc[4][4] = {};

    for (int k0 = 0; k0 < K; k0 += 64) {
        __syncthreads();
        #pragma unroll
        for (int i = 0; i < 4; ++i) {
            const int cbase = (w * 4 + i) * 64;
            const int c = cbase + lane;
            const int r = c >> 3, jc = c & 7;
            const int js = (jc ^ (r & 7)) << 3;
            __builtin_amdgcn_global_load_lds((gvoid_t*)(A  + (rowBase + r) * (long)K + k0 + js),
                                             (svoid_t*)(lA + cbase * 8), 16, 0, 0);
            __builtin_amdgcn_global_load_lds((gvoid_t*)(Bw + (colBase + r) * (long)K + k0 + js),
                                             (svoid_t*)(lB + cbase * 8), 16, 0, 0);
        }
        __syncthreads();

        #pragma unroll
        for (int kk = 0; kk < 2; ++kk) {
            s16x8 af[4], bf[4];
            const int jk = kk * 4 + (lane >> 4);
            #pragma unroll
            for (int mi = 0; mi < 4; ++mi) {
                int r = wr * 64 + mi * 16 + (lane & 15);
                af[mi] = *(const s16x8*)&lA[r * 64 + ((jk ^ (r & 7)) << 3)];
            }
            #pragma unroll
            for (int ni = 0; ni < 4; ++ni) {
                int r = wc * 64 + ni * 16 + (lane & 15);
                bf[ni] = *(const s16x8*)&lB[r * 64 + ((jk ^ (r & 7)) << 3)];
            }
            #pragma unroll
            for (int mi = 0; mi < 4; ++mi)
                #pragma unroll
                for (int ni = 0; ni < 4; ++ni)
                    mfma_bf16(acc[mi][ni], af[mi], bf[ni]);
        }
    }

    asm volatile("s_nop 7\n\ts_nop 7");

    #pragma unroll
    for (int mi = 0; mi < 4; ++mi) {
        #pragma unroll
        for (int ni = 0; ni < 4; ++ni) {
            long col = colBase + wc * 64 + ni * 16 + (lane & 15);
            float bv = bias[col];
            #pragma unroll
            for (int q = 0; q < 4; ++q) {
                long row = rowBase + wr * 64 + mi * 16 + (lane >> 4) * 4 + q;
                C[row * (long)N + col] = acc[mi][ni][q] + bv;
            }
        }
    }
}

extern "C" void kernel_launch(void* const* d_in, const int* in_sizes, int n_in,
                              void* d_out, int out_size, void* d_ws, size_t ws_size,
                              hipStream_t stream) {
    const float* input  = (const float*)d_in[0];
    const float* hidden = (const float*)d_in[1];
    const float* i2h_w  = (const float*)d_in[2];
    const float* i2h_b  = (const float*)d_in[3];
    const float* w_ih   = (const float*)d_in[4];
    const float* w_hh   = (const float*)d_in[5];
    const float* b_ih   = (const float*)d_in[6];
    const float* b_hh   = (const float*)d_in[7];
    const float* dec_w  = (const float*)d_in[8];
    const float* dec_b  = (const float*)d_in[9];

    float* logits = (float*)d_out;                       // [B, OUT]
    float* new_h  = (float*)d_out + (size_t)Bsz * OUTsz; // [L, B, H]

    // Workspace layout (~76 MB)
    char* p = (char*)d_ws;
    unsigned short* wih16  = (unsigned short*)p; p += (size_t)Lsz * 3 * Hsz * Hsz * 2;
    unsigned short* whh16  = (unsigned short*)p; p += (size_t)Lsz * 3 * Hsz * Hsz * 2;
    unsigned short* wdec16 = (unsigned short*)p; p += (size_t)OUTsz * Hsz * 2;
    unsigned short* h16    = (unsigned short*)p; p += (size_t)Lsz * Bsz * Hsz * 2;
    unsigned short* xb0    = (unsigned short*)p; p += (size_t)Bsz * Hsz * 2;
    unsigned short* xb1    = (unsigned short*)p; p += (size_t)Bsz * Hsz * 2;
    unsigned short* xbuf[2] = { xb0, xb1 };

    // 1) ALL pre-work in one grid-stride launch (G11: 4096 blocks)
    prework<<<4096, 256, 0, stream>>>(w_ih, wih16, w_hh, whh16,
                                      dec_w, wdec16, hidden, h16,
                                      input, i2h_w, i2h_b, xb0);

    // 2) fused GRU layers (one launch each; structure-frozen kernel)
    for (int l = 0; l < Lsz; ++l) {
        gru_fused<<<512, 256, 0, stream>>>(
            xbuf[l & 1],
            h16 + (size_t)l * Bsz * Hsz,
            wih16 + (size_t)l * 3 * Hsz * Hsz,
            whh16 + (size_t)l * 3 * Hsz * Hsz,
            b_ih + (size_t)l * 3 * Hsz,
            b_hh + (size_t)l * 3 * Hsz,
            hidden + (size_t)l * Bsz * Hsz,
            new_h + (size_t)l * Bsz * Hsz,
            xbuf[(l + 1) & 1]);
    }

    // 3) decoder: logits = h3 @ dec_w.T + dec_b   (h3 is in xbuf[0] after 4 layers)
    {
        int nx = OUTsz / 128;                          // 2
        int blocks = nx * (Bsz / 128);                 // 32
        gemm_dec<<<blocks, 256, 0, stream>>>(xbuf[Lsz & 1], wdec16, dec_b, logits,
                                             Bsz, OUTsz, Hsz, nx);
    }
}